// Round 2
// baseline (699.393 us; speedup 1.0000x reference)
//
#include <hip/hip_runtime.h>

typedef __attribute__((ext_vector_type(8))) short short8;
typedef __attribute__((ext_vector_type(4))) float f32x4;

#define D_MODEL 1024
#define HEADS 16
#define KD 64
#define SEQ 2048
#define BATCH 4
#define NTOK (BATCH*SEQ)    /* 8192 */
#define QKV_N (3*D_MODEL)   /* 3072 */

__device__ inline float bf2f(unsigned short u) {
    unsigned x = ((unsigned)u) << 16;
    return __builtin_bit_cast(float, x);
}
__device__ inline unsigned short f2bf(float f) {
    unsigned u = __builtin_bit_cast(unsigned, f);
    u += 0x7FFFu + ((u >> 16) & 1u);
    return (unsigned short)(u >> 16);
}

// ---------------------------------------------------------------------------
// Y = X[M,K] @ W[K,N] + bias[N].  W,bias always f32. A_F32: X is f32 else bf16.
// Y_F32: Y is f32 else bf16. f32 accumulate via mfma_16x16x32_bf16.
// 64x64 tile, 4 waves.
// ---------------------------------------------------------------------------
template<int A_F32, int Y_F32>
__global__ __launch_bounds__(256) void gemm_bias_kernel(
    const void* __restrict__ Xv, const float* __restrict__ W,
    const float* __restrict__ bias, void* __restrict__ Yv,
    int M, int N, int K)
{
    __shared__ unsigned short Wt[64][40];   // Wt[n][k], padded stride 40

    const int tid  = threadIdx.x;
    const int lane = tid & 63;
    const int w    = tid >> 6;
    const int l15  = lane & 15, lg = lane >> 4;
    const int n0   = blockIdx.x * 64;
    const int m0   = blockIdx.y * 64;

    f32x4 acc[4] = {{0,0,0,0},{0,0,0,0},{0,0,0,0},{0,0,0,0}};

    const int arow = m0 + w*16 + l15;
    const int kl = tid >> 3;   // 0..31  (k within tile)
    const int n8 = tid & 7;    // 0..7   (8-col group)

    for (int k0 = 0; k0 < K; k0 += 32) {
        // stage W tile (f32 -> bf16, transposed)
        const float* wp = W + (size_t)(k0 + kl) * N + n0 + n8*8;
        f32x4 w0 = *reinterpret_cast<const f32x4*>(wp);
        f32x4 w1 = *reinterpret_cast<const f32x4*>(wp + 4);
        #pragma unroll
        for (int j = 0; j < 4; ++j) {
            Wt[n8*8 + j    ][kl] = f2bf(w0[j]);
            Wt[n8*8 + j + 4][kl] = f2bf(w1[j]);
        }
        __syncthreads();

        short8 a;
        if (A_F32) {
            const float* ap = (const float*)Xv + (size_t)arow * K + k0 + lg*8;
            f32x4 a0 = *reinterpret_cast<const f32x4*>(ap);
            f32x4 a1 = *reinterpret_cast<const f32x4*>(ap + 4);
            #pragma unroll
            for (int j = 0; j < 4; ++j) {
                a[j]     = (short)f2bf(a0[j]);
                a[j + 4] = (short)f2bf(a1[j]);
            }
        } else {
            a = *reinterpret_cast<const short8*>(
                    (const unsigned short*)Xv + (size_t)arow * K + k0 + lg*8);
        }

        #pragma unroll
        for (int t = 0; t < 4; ++t) {
            short8 bfr = *reinterpret_cast<const short8*>(&Wt[l15 + 16*t][lg*8]);
            acc[t] = __builtin_amdgcn_mfma_f32_16x16x32_bf16(a, bfr, acc[t], 0, 0, 0);
        }
        __syncthreads();
    }

    #pragma unroll
    for (int t = 0; t < 4; ++t) {
        int col = n0 + l15 + 16*t;
        float bv = bias[col];
        #pragma unroll
        for (int r = 0; r < 4; ++r) {
            int row = m0 + w*16 + lg*4 + r;
            float v = acc[t][r] + bv;
            if (Y_F32) ((float*)Yv)[(size_t)row * N + col] = v;
            else       ((unsigned short*)Yv)[(size_t)row * N + col] = f2bf(v);
        }
    }
}

// ---------------------------------------------------------------------------
// present[2,B,H,S,64] (f32): [0]=key (qkv col 2048+h*64), [1]=value (col h*64)
// qkv is bf16 workspace.
// ---------------------------------------------------------------------------
__global__ __launch_bounds__(256) void present_kernel(
    const unsigned short* __restrict__ qkv, float* __restrict__ pres)
{
    int i  = blockIdx.x * 256 + threadIdx.x;   // 0 .. 2*B*H*S*8-1
    int d8 = i & 7;
    int s  = (i >> 3)  & (SEQ - 1);
    int h  = (i >> 14) & (HEADS - 1);
    int bb = (i >> 18) & 3;
    int kv = i >> 20;
    int col = (kv == 0 ? 2*D_MODEL : 0) + h*KD + d8*8;
    short8 v = *reinterpret_cast<const short8*>(
        qkv + (size_t)(bb*SEQ + s) * QKV_N + col);
    f32x4 lo, hi;
    #pragma unroll
    for (int j = 0; j < 4; ++j) {
        lo[j] = bf2f((unsigned short)v[j]);
        hi[j] = bf2f((unsigned short)v[j + 4]);
    }
    *reinterpret_cast<f32x4*>(pres + (size_t)i * 8)     = lo;
    *reinterpret_cast<f32x4*>(pres + (size_t)i * 8 + 4) = hi;
}

// ---------------------------------------------------------------------------
// Flash-style causal attention on bf16 qkv workspace -> bf16 aout.
// Block = (qt, h, b): 64 q-rows, 4 waves x 16 rows.
// qkv row layout: [value(1024) | query(1024) | key(1024)]
// ---------------------------------------------------------------------------
__global__ __launch_bounds__(256) void attn_kernel(
    const unsigned short* __restrict__ qkv, unsigned short* __restrict__ aout)
{
    __shared__ unsigned short Kl[64][72];      // Kl[key][d]
    __shared__ unsigned short Vt[64][72];      // Vt[d][key]
    __shared__ unsigned short Pl[4][16][72];   // per-wave P tile [qrow][key]

    const int tid  = threadIdx.x;
    const int lane = tid & 63;
    const int w    = tid >> 6;
    const int l15  = lane & 15, lg = lane >> 4;

    const int qt = blockIdx.x;   // 0..31
    const int h  = blockIdx.y;   // 0..15
    const int b  = blockIdx.z;   // 0..3
    const int q0 = qt * 64;

    const unsigned short* base = qkv + (size_t)b * SEQ * QKV_N;
    const int qoff = D_MODEL + h*KD;
    const int koff = 2*D_MODEL + h*KD;
    const int voff = h*KD;

    const int qrow = q0 + w*16 + l15;
    short8 aq0 = *reinterpret_cast<const short8*>(base + (size_t)qrow * QKV_N + qoff + lg*8);
    short8 aq1 = *reinterpret_cast<const short8*>(base + (size_t)qrow * QKV_N + qoff + 32 + lg*8);

    f32x4 o[4] = {{0,0,0,0},{0,0,0,0},{0,0,0,0},{0,0,0,0}};
    float mr[4] = {-1e30f, -1e30f, -1e30f, -1e30f};
    float sr[4] = {0.f, 0.f, 0.f, 0.f};

    const int key8 = tid >> 3;  // 0..31
    const int d8   = tid & 7;   // 0..7

    for (int kt = 0; kt <= qt; ++kt) {
        __syncthreads();
        #pragma unroll
        for (int half = 0; half < 2; ++half) {
            int key = key8 + half*32;
            const unsigned short* krow = base + (size_t)(kt*64 + key) * QKV_N;
            short8 kv = *reinterpret_cast<const short8*>(krow + koff + d8*8);
            *reinterpret_cast<short8*>(&Kl[key][d8*8]) = kv;
            short8 vv = *reinterpret_cast<const short8*>(krow + voff + d8*8);
            #pragma unroll
            for (int j = 0; j < 8; ++j) Vt[d8*8 + j][key] = (unsigned short)vv[j];
        }
        __syncthreads();

        // QK^T : scores 16(q) x 64(keys) per wave
        f32x4 s[4] = {{0,0,0,0},{0,0,0,0},{0,0,0,0},{0,0,0,0}};
        #pragma unroll
        for (int t = 0; t < 4; ++t) {
            short8 bk0 = *reinterpret_cast<const short8*>(&Kl[l15 + 16*t][lg*8]);
            short8 bk1 = *reinterpret_cast<const short8*>(&Kl[l15 + 16*t][32 + lg*8]);
            s[t] = __builtin_amdgcn_mfma_f32_16x16x32_bf16(aq0, bk0, s[t], 0, 0, 0);
            s[t] = __builtin_amdgcn_mfma_f32_16x16x32_bf16(aq1, bk1, s[t], 0, 0, 0);
        }

        const bool diag = (kt == qt);
        float p[4][4];
        float lm[4] = {-1e30f, -1e30f, -1e30f, -1e30f};
        #pragma unroll
        for (int t = 0; t < 4; ++t) {
            #pragma unroll
            for (int r = 0; r < 4; ++r) {
                float sv = s[t][r] * 0.125f;
                if (diag) {
                    int rowl = w*16 + lg*4 + r;
                    int coll = l15 + 16*t;
                    if (coll > rowl) sv = -1e30f;
                }
                p[t][r] = sv;
                lm[r] = fmaxf(lm[r], sv);
            }
        }
        #pragma unroll
        for (int off = 1; off < 16; off <<= 1) {
            #pragma unroll
            for (int r = 0; r < 4; ++r) lm[r] = fmaxf(lm[r], __shfl_xor(lm[r], off, 64));
        }
        float fac[4];
        #pragma unroll
        for (int r = 0; r < 4; ++r) {
            float nm = fmaxf(mr[r], lm[r]);
            fac[r] = expf(mr[r] - nm);
            mr[r] = nm;
        }
        float tsum[4] = {0.f, 0.f, 0.f, 0.f};
        #pragma unroll
        for (int t = 0; t < 4; ++t) {
            #pragma unroll
            for (int r = 0; r < 4; ++r) {
                float pv = expf(p[t][r] - mr[r]);
                p[t][r] = pv;
                tsum[r] += pv;
            }
        }
        #pragma unroll
        for (int off = 1; off < 16; off <<= 1) {
            #pragma unroll
            for (int r = 0; r < 4; ++r) tsum[r] += __shfl_xor(tsum[r], off, 64);
        }
        #pragma unroll
        for (int r = 0; r < 4; ++r) sr[r] = sr[r] * fac[r] + tsum[r];
        #pragma unroll
        for (int t2 = 0; t2 < 4; ++t2) {
            #pragma unroll
            for (int r = 0; r < 4; ++r) o[t2][r] *= fac[r];
        }

        // P -> wave-private LDS (D-layout) -> A-fragment layout
        #pragma unroll
        for (int t = 0; t < 4; ++t) {
            #pragma unroll
            for (int r = 0; r < 4; ++r)
                Pl[w][lg*4 + r][l15 + 16*t] = f2bf(p[t][r]);
        }
        short8 pa0 = *reinterpret_cast<const short8*>(&Pl[w][l15][lg*8]);
        short8 pa1 = *reinterpret_cast<const short8*>(&Pl[w][l15][32 + lg*8]);

        #pragma unroll
        for (int t2 = 0; t2 < 4; ++t2) {
            short8 bv0 = *reinterpret_cast<const short8*>(&Vt[l15 + 16*t2][lg*8]);
            short8 bv1 = *reinterpret_cast<const short8*>(&Vt[l15 + 16*t2][32 + lg*8]);
            o[t2] = __builtin_amdgcn_mfma_f32_16x16x32_bf16(pa0, bv0, o[t2], 0, 0, 0);
            o[t2] = __builtin_amdgcn_mfma_f32_16x16x32_bf16(pa1, bv1, o[t2], 0, 0, 0);
        }
    }

    #pragma unroll
    for (int t2 = 0; t2 < 4; ++t2) {
        #pragma unroll
        for (int r = 0; r < 4; ++r) {
            int row = q0 + w*16 + lg*4 + r;
            aout[((size_t)b * SEQ + row) * D_MODEL + h*KD + l15 + 16*t2] =
                f2bf(o[t2][r] / sr[r]);
        }
    }
}

// ---------------------------------------------------------------------------
extern "C" void kernel_launch(void* const* d_in, const int* in_sizes, int n_in,
                              void* d_out, int out_size, void* d_ws, size_t ws_size,
                              hipStream_t stream)
{
    const float* x      = (const float*)d_in[0];
    const float* W_attn = (const float*)d_in[1];
    const float* b_attn = (const float*)d_in[2];
    const float* W_proj = (const float*)d_in[3];
    const float* b_proj = (const float*)d_in[4];
    float* out = (float*)d_out;

    unsigned short* qkv  = (unsigned short*)d_ws;                 // [8192, 3072] bf16
    unsigned short* aout = qkv + (size_t)NTOK * QKV_N;            // [8192, 1024] bf16

    // qkv = x @ W_attn + b_attn   (f32 in -> bf16 ws)
    dim3 g1(QKV_N / 64, NTOK / 64);
    gemm_bias_kernel<1, 0><<<g1, 256, 0, stream>>>(x, W_attn, b_attn, qkv,
                                                   NTOK, QKV_N, D_MODEL);

    // present = stack(k, v)  (bf16 ws -> f32 out)
    present_kernel<<<(2 * BATCH * HEADS * SEQ * 8) / 256, 256, 0, stream>>>(
        qkv, out + (size_t)NTOK * D_MODEL);

    // causal attention (bf16 ws -> bf16 ws)
    dim3 ga(SEQ / 64, HEADS, BATCH);
    attn_kernel<<<ga, 256, 0, stream>>>(qkv, aout);

    // out = aout @ W_proj + b_proj  (bf16 ws -> f32 out)
    dim3 g2(D_MODEL / 64, NTOK / 64);
    gemm_bias_kernel<0, 1><<<g2, 256, 0, stream>>>(aout, W_proj, b_proj, out,
                                                   NTOK, D_MODEL, D_MODEL);
}

// Round 3
// 419.619 us; speedup vs baseline: 1.6667x; 1.6667x over previous
//
#include <hip/hip_runtime.h>

typedef __attribute__((ext_vector_type(8))) short short8;
typedef __attribute__((ext_vector_type(4))) float f32x4;

#define D_MODEL 1024
#define HEADS 16
#define KD 64
#define SEQ 2048
#define BATCH 4
#define NTOK (BATCH*SEQ)    /* 8192 */
#define QKV_N (3*D_MODEL)   /* 3072 */

__device__ inline float bf2f(unsigned short u) {
    unsigned x = ((unsigned)u) << 16;
    return __builtin_bit_cast(float, x);
}
__device__ inline unsigned short f2bf(float f) {
    unsigned u = __builtin_bit_cast(unsigned, f);
    u += 0x7FFFu + ((u >> 16) & 1u);
    return (unsigned short)(u >> 16);
}
__device__ __forceinline__ void gload_lds16(const unsigned short* g, unsigned short* l) {
    __builtin_amdgcn_global_load_lds(
        (const __attribute__((address_space(1))) void*)g,
        (__attribute__((address_space(3))) void*)l, 16, 0, 0);
}

// ---------------------------------------------------------------------------
// x (f32) -> bf16, elementwise, 8 per thread
// ---------------------------------------------------------------------------
__global__ __launch_bounds__(256) void cvt_kernel(
    const float* __restrict__ x, unsigned short* __restrict__ y)
{
    size_t i = (size_t)blockIdx.x * 256 + threadIdx.x;
    f32x4 a = *reinterpret_cast<const f32x4*>(x + i*8);
    f32x4 b = *reinterpret_cast<const f32x4*>(x + i*8 + 4);
    short8 o;
    #pragma unroll
    for (int j = 0; j < 4; ++j) { o[j] = (short)f2bf(a[j]); o[j+4] = (short)f2bf(b[j]); }
    *reinterpret_cast<short8*>(y + i*8) = o;
}

// ---------------------------------------------------------------------------
// WT[n][k] = bf16(W[k][n]); tile 64x64 via LDS
// ---------------------------------------------------------------------------
__global__ __launch_bounds__(256) void transpose_kernel(
    const float* __restrict__ W, unsigned short* __restrict__ WT, int K, int N)
{
    __shared__ unsigned short T[64][80];   // padded, rows 160B (16B-aligned)
    const int tid = threadIdx.x;
    const int n0 = blockIdx.x * 64, k0 = blockIdx.y * 64;

    int r  = tid >> 2;        // k within tile
    int cq = tid & 3;         // 16-col group
    const float* src = W + (size_t)(k0 + r) * N + n0 + cq*16;
    #pragma unroll
    for (int q = 0; q < 4; ++q) {
        f32x4 v = *reinterpret_cast<const f32x4*>(src + q*4);
        #pragma unroll
        for (int j = 0; j < 4; ++j) T[cq*16 + q*4 + j][r] = f2bf(v[j]);
    }
    __syncthreads();
    int c  = tid >> 2;        // n within tile
    int rq = tid & 3;         // 16-k group
    short8 o0 = *reinterpret_cast<const short8*>(&T[c][rq*16]);
    short8 o1 = *reinterpret_cast<const short8*>(&T[c][rq*16 + 8]);
    unsigned short* dst = WT + (size_t)(n0 + c) * K + k0 + rq*16;
    *reinterpret_cast<short8*>(dst)     = o0;
    *reinterpret_cast<short8*>(dst + 8) = o1;
}

// ---------------------------------------------------------------------------
// Y = A[M,K](bf16) @ BT[N,K]^T(bf16) + bias(f32).  128x128 tile, BK=64,
// 4 waves (2x2), global_load_lds w/ pre-swizzled source, swizzled ds_read.
// ---------------------------------------------------------------------------
template<int Y_F32>
__global__ __launch_bounds__(256) void gemm_bt_kernel(
    const unsigned short* __restrict__ A, const unsigned short* __restrict__ BT,
    const float* __restrict__ bias, void* __restrict__ Yv,
    int M, int N, int K)
{
    __shared__ unsigned short sA[128*64];   // [row][chunk^(row&7)]  chunks of 8 bf16
    __shared__ unsigned short sB[128*64];

    const int tid = threadIdx.x, lane = tid & 63, w = tid >> 6;
    const int l15 = lane & 15, lg = lane >> 4;
    const int n0 = blockIdx.x * 128, m0 = blockIdx.y * 128;
    const int wr = w >> 1, wc = w & 1;

    f32x4 acc[4][4];
    #pragma unroll
    for (int m = 0; m < 4; ++m)
        #pragma unroll
        for (int n = 0; n < 4; ++n) acc[m][n] = f32x4{0,0,0,0};

    const int ldrow = (lane >> 3);        // row within KB
    const int slot  = lane & 7;

    for (int k0 = 0; k0 < K; k0 += 64) {
        #pragma unroll
        for (int i = 0; i < 4; ++i) {
            int kb  = w*4 + i;                 // 0..15
            int row = kb*8 + ldrow;            // 0..127
            int sc  = slot ^ (row & 7);        // inverse-swizzled source chunk
            gload_lds16(&A [(size_t)(m0 + row) * K + k0 + sc*8], &sA[kb*512]);
            gload_lds16(&BT[(size_t)(n0 + row) * K + k0 + sc*8], &sB[kb*512]);
        }
        __syncthreads();   // drains vmcnt: tiles visible

        #pragma unroll
        for (int kk = 0; kk < 2; ++kk) {
            short8 af[4], bf[4];
            #pragma unroll
            for (int m = 0; m < 4; ++m) {
                int row = wr*64 + m*16 + l15;
                int ch  = (4*kk + lg) ^ (row & 7);
                af[m] = *reinterpret_cast<const short8*>(&sA[row*64 + ch*8]);
            }
            #pragma unroll
            for (int n = 0; n < 4; ++n) {
                int row = wc*64 + n*16 + l15;
                int ch  = (4*kk + lg) ^ (row & 7);
                bf[n] = *reinterpret_cast<const short8*>(&sB[row*64 + ch*8]);
            }
            #pragma unroll
            for (int m = 0; m < 4; ++m)
                #pragma unroll
                for (int n = 0; n < 4; ++n)
                    acc[m][n] = __builtin_amdgcn_mfma_f32_16x16x32_bf16(
                        af[m], bf[n], acc[m][n], 0, 0, 0);
        }
        __syncthreads();   // all reads done before next overwrite
    }

    #pragma unroll
    for (int n = 0; n < 4; ++n) {
        int col = n0 + wc*64 + n*16 + l15;
        float bv = bias[col];
        #pragma unroll
        for (int m = 0; m < 4; ++m) {
            #pragma unroll
            for (int r = 0; r < 4; ++r) {
                int row = m0 + wr*64 + m*16 + lg*4 + r;
                float v = acc[m][n][r] + bv;
                if (Y_F32) ((float*)Yv)[(size_t)row * N + col] = v;
                else       ((unsigned short*)Yv)[(size_t)row * N + col] = f2bf(v);
            }
        }
    }
}

// ---------------------------------------------------------------------------
// present[2,B,H,S,64] (f32): [0]=key (qkv col 2048+h*64), [1]=value (col h*64)
// ---------------------------------------------------------------------------
__global__ __launch_bounds__(256) void present_kernel(
    const unsigned short* __restrict__ qkv, float* __restrict__ pres)
{
    int i  = blockIdx.x * 256 + threadIdx.x;
    int d8 = i & 7;
    int s  = (i >> 3)  & (SEQ - 1);
    int h  = (i >> 14) & (HEADS - 1);
    int bb = (i >> 18) & 3;
    int kv = i >> 20;
    int col = (kv == 0 ? 2*D_MODEL : 0) + h*KD + d8*8;
    short8 v = *reinterpret_cast<const short8*>(
        qkv + (size_t)(bb*SEQ + s) * QKV_N + col);
    f32x4 lo, hi;
    #pragma unroll
    for (int j = 0; j < 4; ++j) {
        lo[j] = bf2f((unsigned short)v[j]);
        hi[j] = bf2f((unsigned short)v[j + 4]);
    }
    *reinterpret_cast<f32x4*>(pres + (size_t)i * 8)     = lo;
    *reinterpret_cast<f32x4*>(pres + (size_t)i * 8 + 4) = hi;
}

// ---------------------------------------------------------------------------
// Flash-style causal attention. 64 q-rows/block, 4 waves x 16 rows.
// XOR-swizzled K/V tiles [64][64], double-buffered, 1 barrier/iter,
// next-tile global loads issued before compute. log2-domain softmax.
// ---------------------------------------------------------------------------
__global__ __launch_bounds__(256) void attn_kernel(
    const unsigned short* __restrict__ qkv, unsigned short* __restrict__ aout)
{
    __shared__ unsigned short Kl[2][64*64];
    __shared__ unsigned short Vt[2][64*64];
    __shared__ unsigned short Pl[4][16][72];

    const int tid  = threadIdx.x;
    const int lane = tid & 63;
    const int w    = tid >> 6;
    const int l15  = lane & 15, lg = lane >> 4;

    const int qt = blockIdx.x;
    const int h  = blockIdx.y;
    const int b  = blockIdx.z;
    const int q0 = qt * 64;

    const unsigned short* base = qkv + (size_t)b * SEQ * QKV_N;
    const int qoff = D_MODEL + h*KD;
    const int koff = 2*D_MODEL + h*KD;
    const int voff = h*KD;

    const int qrow = q0 + w*16 + l15;
    short8 aq0 = *reinterpret_cast<const short8*>(base + (size_t)qrow * QKV_N + qoff + lg*8);
    short8 aq1 = *reinterpret_cast<const short8*>(base + (size_t)qrow * QKV_N + qoff + 32 + lg*8);

    f32x4 o[4] = {{0,0,0,0},{0,0,0,0},{0,0,0,0},{0,0,0,0}};
    float mr[4] = {-1e30f, -1e30f, -1e30f, -1e30f};
    float sr[4] = {0.f, 0.f, 0.f, 0.f};

    const int key8 = tid >> 3;  // 0..31
    const int d8   = tid & 7;   // 0..7
    const float SCALE2 = 0.125f * 1.44269504088896f;   // 1/sqrt(64) * log2(e)

    short8 kreg[2], vreg[2];

    // prologue: stage tile 0
    #pragma unroll
    for (int half = 0; half < 2; ++half) {
        int key = key8 + half*32;
        const unsigned short* krow = base + (size_t)key * QKV_N;
        kreg[half] = *reinterpret_cast<const short8*>(krow + koff + d8*8);
        vreg[half] = *reinterpret_cast<const short8*>(krow + voff + d8*8);
    }
    #pragma unroll
    for (int half = 0; half < 2; ++half) {
        int key = key8 + half*32;
        int sk = (key & 7) ^ ((key >> 3) & 7);
        *reinterpret_cast<short8*>(&Kl[0][key*64 + (d8 ^ sk)*8]) = kreg[half];
        #pragma unroll
        for (int j = 0; j < 8; ++j) {
            int d  = d8*8 + j;
            int sd = j ^ d8;                       // (d&7)^((d>>3)&7)
            Vt[0][d*64 + (((key >> 3) ^ sd) << 3) + (key & 7)] =
                (unsigned short)vreg[half][j];
        }
    }
    __syncthreads();

    for (int kt = 0; kt <= qt; ++kt) {
        const int buf = kt & 1;

        if (kt < qt) {   // issue next-tile global loads (hidden under compute)
            #pragma unroll
            for (int half = 0; half < 2; ++half) {
                int key = key8 + half*32;
                const unsigned short* krow = base + (size_t)((kt+1)*64 + key) * QKV_N;
                kreg[half] = *reinterpret_cast<const short8*>(krow + koff + d8*8);
                vreg[half] = *reinterpret_cast<const short8*>(krow + voff + d8*8);
            }
        }

        // QK^T : 16(q) x 64(keys) per wave
        f32x4 s[4] = {{0,0,0,0},{0,0,0,0},{0,0,0,0},{0,0,0,0}};
        #pragma unroll
        for (int t = 0; t < 4; ++t) {
            int row = l15 + 16*t;
            int sw  = (row & 7) ^ ((row >> 3) & 7);
            short8 bk0 = *reinterpret_cast<const short8*>(&Kl[buf][row*64 + (lg ^ sw)*8]);
            short8 bk1 = *reinterpret_cast<const short8*>(&Kl[buf][row*64 + ((lg+4) ^ sw)*8]);
            s[t] = __builtin_amdgcn_mfma_f32_16x16x32_bf16(aq0, bk0, s[t], 0, 0, 0);
            s[t] = __builtin_amdgcn_mfma_f32_16x16x32_bf16(aq1, bk1, s[t], 0, 0, 0);
        }

        const bool diag = (kt == qt);
        float p[4][4];
        float lm[4] = {-1e30f, -1e30f, -1e30f, -1e30f};
        #pragma unroll
        for (int t = 0; t < 4; ++t) {
            #pragma unroll
            for (int r = 0; r < 4; ++r) {
                float sv = s[t][r] * SCALE2;
                if (diag) {
                    int rowl = w*16 + lg*4 + r;
                    int coll = l15 + 16*t;
                    if (coll > rowl) sv = -1e30f;
                }
                p[t][r] = sv;
                lm[r] = fmaxf(lm[r], sv);
            }
        }
        #pragma unroll
        for (int off = 1; off < 16; off <<= 1) {
            #pragma unroll
            for (int r = 0; r < 4; ++r) lm[r] = fmaxf(lm[r], __shfl_xor(lm[r], off, 64));
        }
        float fac[4];
        #pragma unroll
        for (int r = 0; r < 4; ++r) {
            float nm = fmaxf(mr[r], lm[r]);
            fac[r] = exp2f(mr[r] - nm);
            mr[r] = nm;
        }
        float tsum[4] = {0.f, 0.f, 0.f, 0.f};
        #pragma unroll
        for (int t = 0; t < 4; ++t) {
            #pragma unroll
            for (int r = 0; r < 4; ++r) {
                float pv = exp2f(p[t][r] - mr[r]);
                p[t][r] = pv;
                tsum[r] += pv;
            }
        }
        #pragma unroll
        for (int off = 1; off < 16; off <<= 1) {
            #pragma unroll
            for (int r = 0; r < 4; ++r) tsum[r] += __shfl_xor(tsum[r], off, 64);
        }
        #pragma unroll
        for (int r = 0; r < 4; ++r) sr[r] = sr[r] * fac[r] + tsum[r];
        #pragma unroll
        for (int t2 = 0; t2 < 4; ++t2) {
            #pragma unroll
            for (int r = 0; r < 4; ++r) o[t2][r] *= fac[r];
        }

        // P -> wave-private LDS (D-layout) -> A-fragment layout
        #pragma unroll
        for (int t = 0; t < 4; ++t) {
            #pragma unroll
            for (int r = 0; r < 4; ++r)
                Pl[w][lg*4 + r][l15 + 16*t] = f2bf(p[t][r]);
        }
        short8 pa0 = *reinterpret_cast<const short8*>(&Pl[w][l15][lg*8]);
        short8 pa1 = *reinterpret_cast<const short8*>(&Pl[w][l15][32 + lg*8]);

        #pragma unroll
        for (int t2 = 0; t2 < 4; ++t2) {
            int row = l15 + 16*t2;
            int sw  = (row & 7) ^ ((row >> 3) & 7);
            short8 bv0 = *reinterpret_cast<const short8*>(&Vt[buf][row*64 + (lg ^ sw)*8]);
            short8 bv1 = *reinterpret_cast<const short8*>(&Vt[buf][row*64 + ((lg+4) ^ sw)*8]);
            o[t2] = __builtin_amdgcn_mfma_f32_16x16x32_bf16(pa0, bv0, o[t2], 0, 0, 0);
            o[t2] = __builtin_amdgcn_mfma_f32_16x16x32_bf16(pa1, bv1, o[t2], 0, 0, 0);
        }

        if (kt < qt) {   // write next tile to other buffer
            #pragma unroll
            for (int half = 0; half < 2; ++half) {
                int key = key8 + half*32;
                int sk = (key & 7) ^ ((key >> 3) & 7);
                *reinterpret_cast<short8*>(&Kl[buf^1][key*64 + (d8 ^ sk)*8]) = kreg[half];
                #pragma unroll
                for (int j = 0; j < 8; ++j) {
                    int d  = d8*8 + j;
                    int sd = j ^ d8;
                    Vt[buf^1][d*64 + (((key >> 3) ^ sd) << 3) + (key & 7)] =
                        (unsigned short)vreg[half][j];
                }
            }
        }
        __syncthreads();
    }

    #pragma unroll
    for (int t2 = 0; t2 < 4; ++t2) {
        #pragma unroll
        for (int r = 0; r < 4; ++r) {
            int row = q0 + w*16 + lg*4 + r;
            aout[((size_t)b * SEQ + row) * D_MODEL + h*KD + l15 + 16*t2] =
                f2bf(o[t2][r] / sr[r]);
        }
    }
}

// ---------------------------------------------------------------------------
extern "C" void kernel_launch(void* const* d_in, const int* in_sizes, int n_in,
                              void* d_out, int out_size, void* d_ws, size_t ws_size,
                              hipStream_t stream)
{
    const float* x      = (const float*)d_in[0];
    const float* W_attn = (const float*)d_in[1];
    const float* b_attn = (const float*)d_in[2];
    const float* W_proj = (const float*)d_in[3];
    const float* b_proj = (const float*)d_in[4];
    float* out = (float*)d_out;

    unsigned short* qkv  = (unsigned short*)d_ws;                  // [8192][3072]
    unsigned short* xbf  = qkv + (size_t)NTOK * QKV_N;             // [8192][1024] (aliases aout)
    unsigned short* aout = xbf;                                    // x dead after GEMM1
    unsigned short* WT   = xbf + (size_t)NTOK * D_MODEL;           // [3072][1024]
    unsigned short* WpT  = WT + (size_t)QKV_N * D_MODEL;           // [1024][1024]

    // prep: convert x, transpose+convert weights
    cvt_kernel<<<(NTOK * D_MODEL / 8) / 256, 256, 0, stream>>>(x, xbf);
    dim3 gt1(QKV_N / 64, D_MODEL / 64);
    transpose_kernel<<<gt1, 256, 0, stream>>>(W_attn, WT, D_MODEL, QKV_N);
    dim3 gt2(D_MODEL / 64, D_MODEL / 64);
    transpose_kernel<<<gt2, 256, 0, stream>>>(W_proj, WpT, D_MODEL, D_MODEL);

    // qkv = x @ W_attn + b_attn
    dim3 g1(QKV_N / 128, NTOK / 128);
    gemm_bt_kernel<0><<<g1, 256, 0, stream>>>(xbf, WT, b_attn, qkv,
                                              NTOK, QKV_N, D_MODEL);

    // present = stack(k, v)
    present_kernel<<<(2 * BATCH * HEADS * SEQ * 8) / 256, 256, 0, stream>>>(
        qkv, out + (size_t)NTOK * D_MODEL);

    // causal attention
    dim3 ga(SEQ / 64, HEADS, BATCH);
    attn_kernel<<<ga, 256, 0, stream>>>(qkv, aout);

    // out = aout @ W_proj + b_proj
    dim3 g2(D_MODEL / 128, NTOK / 128);
    gemm_bt_kernel<1><<<g2, 256, 0, stream>>>(aout, WpT, b_proj, out,
                                              NTOK, D_MODEL, D_MODEL);
}

// Round 4
// 367.905 us; speedup vs baseline: 1.9010x; 1.1406x over previous
//
#include <hip/hip_runtime.h>

typedef __attribute__((ext_vector_type(8))) short short8;
typedef __attribute__((ext_vector_type(4))) short short4v;
typedef __attribute__((ext_vector_type(4))) float f32x4;

#define D_MODEL 1024
#define HEADS 16
#define KD 64
#define SEQ 2048
#define BATCH 4
#define NTOK (BATCH*SEQ)    /* 8192 */
#define QKV_N (3*D_MODEL)   /* 3072 */

__device__ inline float bf2f(unsigned short u) {
    unsigned x = ((unsigned)u) << 16;
    return __builtin_bit_cast(float, x);
}
__device__ inline unsigned short f2bf(float f) {
    unsigned u = __builtin_bit_cast(unsigned, f);
    u += 0x7FFFu + ((u >> 16) & 1u);
    return (unsigned short)(u >> 16);
}
__device__ __forceinline__ void gload_lds16(const unsigned short* g, unsigned short* l) {
    __builtin_amdgcn_global_load_lds(
        (const __attribute__((address_space(1))) void*)g,
        (__attribute__((address_space(3))) void*)l, 16, 0, 0);
}

// ---------------------------------------------------------------------------
// x (f32) -> bf16, elementwise, 8 per thread
// ---------------------------------------------------------------------------
__global__ __launch_bounds__(256) void cvt_kernel(
    const float* __restrict__ x, unsigned short* __restrict__ y)
{
    size_t i = (size_t)blockIdx.x * 256 + threadIdx.x;
    f32x4 a = *reinterpret_cast<const f32x4*>(x + i*8);
    f32x4 b = *reinterpret_cast<const f32x4*>(x + i*8 + 4);
    short8 o;
    #pragma unroll
    for (int j = 0; j < 4; ++j) { o[j] = (short)f2bf(a[j]); o[j+4] = (short)f2bf(b[j]); }
    *reinterpret_cast<short8*>(y + i*8) = o;
}

// ---------------------------------------------------------------------------
// WT[n][k] = bf16(W[k][n]); tile 64x64 via LDS
// ---------------------------------------------------------------------------
__global__ __launch_bounds__(256) void transpose_kernel(
    const float* __restrict__ W, unsigned short* __restrict__ WT, int K, int N)
{
    __shared__ unsigned short T[64][80];
    const int tid = threadIdx.x;
    const int n0 = blockIdx.x * 64, k0 = blockIdx.y * 64;

    int r  = tid >> 2;
    int cq = tid & 3;
    const float* src = W + (size_t)(k0 + r) * N + n0 + cq*16;
    #pragma unroll
    for (int q = 0; q < 4; ++q) {
        f32x4 v = *reinterpret_cast<const f32x4*>(src + q*4);
        #pragma unroll
        for (int j = 0; j < 4; ++j) T[cq*16 + q*4 + j][r] = f2bf(v[j]);
    }
    __syncthreads();
    int c  = tid >> 2;
    int rq = tid & 3;
    short8 o0 = *reinterpret_cast<const short8*>(&T[c][rq*16]);
    short8 o1 = *reinterpret_cast<const short8*>(&T[c][rq*16 + 8]);
    unsigned short* dst = WT + (size_t)(n0 + c) * K + k0 + rq*16;
    *reinterpret_cast<short8*>(dst)     = o0;
    *reinterpret_cast<short8*>(dst + 8) = o1;
}

// ---------------------------------------------------------------------------
// Y = A[M,K](bf16) @ BT[N,K]^T(bf16) + bias(f32).  128x128 tile, BK=64,
// 4 waves (2x2), global_load_lds w/ pre-swizzled source, swizzled ds_read.
// VTG: for cols < D_MODEL also write vtg[b][h][d][s] (transposed V, bf16).
// ---------------------------------------------------------------------------
template<int Y_F32, int VTG>
__global__ __launch_bounds__(256) void gemm_bt_kernel(
    const unsigned short* __restrict__ A, const unsigned short* __restrict__ BT,
    const float* __restrict__ bias, void* __restrict__ Yv,
    unsigned short* __restrict__ vtg,
    int M, int N, int K)
{
    __shared__ unsigned short sA[128*64];
    __shared__ unsigned short sB[128*64];

    const int tid = threadIdx.x, lane = tid & 63, w = tid >> 6;
    const int l15 = lane & 15, lg = lane >> 4;
    const int n0 = blockIdx.x * 128, m0 = blockIdx.y * 128;
    const int wr = w >> 1, wc = w & 1;

    f32x4 acc[4][4];
    #pragma unroll
    for (int m = 0; m < 4; ++m)
        #pragma unroll
        for (int n = 0; n < 4; ++n) acc[m][n] = f32x4{0,0,0,0};

    const int ldrow = (lane >> 3);
    const int slot  = lane & 7;

    for (int k0 = 0; k0 < K; k0 += 64) {
        #pragma unroll
        for (int i = 0; i < 4; ++i) {
            int kb  = w*4 + i;
            int row = kb*8 + ldrow;
            int sc  = slot ^ (row & 7);
            gload_lds16(&A [(size_t)(m0 + row) * K + k0 + sc*8], &sA[kb*512]);
            gload_lds16(&BT[(size_t)(n0 + row) * K + k0 + sc*8], &sB[kb*512]);
        }
        __syncthreads();

        #pragma unroll
        for (int kk = 0; kk < 2; ++kk) {
            short8 af[4], bfr[4];
            #pragma unroll
            for (int m = 0; m < 4; ++m) {
                int row = wr*64 + m*16 + l15;
                int ch  = (4*kk + lg) ^ (row & 7);
                af[m] = *reinterpret_cast<const short8*>(&sA[row*64 + ch*8]);
            }
            #pragma unroll
            for (int n = 0; n < 4; ++n) {
                int row = wc*64 + n*16 + l15;
                int ch  = (4*kk + lg) ^ (row & 7);
                bfr[n] = *reinterpret_cast<const short8*>(&sB[row*64 + ch*8]);
            }
            #pragma unroll
            for (int m = 0; m < 4; ++m)
                #pragma unroll
                for (int n = 0; n < 4; ++n)
                    acc[m][n] = __builtin_amdgcn_mfma_f32_16x16x32_bf16(
                        af[m], bfr[n], acc[m][n], 0, 0, 0);
        }
        __syncthreads();
    }

    #pragma unroll
    for (int n = 0; n < 4; ++n) {
        int col = n0 + wc*64 + n*16 + l15;
        float bv = bias[col];
        #pragma unroll
        for (int m = 0; m < 4; ++m) {
            int row0 = m0 + wr*64 + m*16 + lg*4;
            float v0 = acc[m][n][0] + bv;
            float v1 = acc[m][n][1] + bv;
            float v2 = acc[m][n][2] + bv;
            float v3 = acc[m][n][3] + bv;
            if (Y_F32) {
                float* Y = (float*)Yv;
                Y[(size_t)(row0+0) * N + col] = v0;
                Y[(size_t)(row0+1) * N + col] = v1;
                Y[(size_t)(row0+2) * N + col] = v2;
                Y[(size_t)(row0+3) * N + col] = v3;
            } else {
                unsigned short* Y = (unsigned short*)Yv;
                Y[(size_t)(row0+0) * N + col] = f2bf(v0);
                Y[(size_t)(row0+1) * N + col] = f2bf(v1);
                Y[(size_t)(row0+2) * N + col] = f2bf(v2);
                Y[(size_t)(row0+3) * N + col] = f2bf(v3);
            }
            if (VTG && n0 < D_MODEL) {   // V columns: also write transposed copy
                int hh = col >> 6, dd = col & 63;
                int bb = row0 >> 11, ss = row0 & (SEQ - 1);
                short4v pk;
                pk[0] = (short)f2bf(v0); pk[1] = (short)f2bf(v1);
                pk[2] = (short)f2bf(v2); pk[3] = (short)f2bf(v3);
                *reinterpret_cast<short4v*>(
                    vtg + (((size_t)bb*HEADS + hh)*KD + dd)*SEQ + ss) = pk;
            }
        }
    }
}

// ---------------------------------------------------------------------------
// present[2,B,H,S,64] (f32): [0]=key (qkv col 2048+h*64), [1]=value (col h*64)
// ---------------------------------------------------------------------------
__global__ __launch_bounds__(256) void present_kernel(
    const unsigned short* __restrict__ qkv, float* __restrict__ pres)
{
    int i  = blockIdx.x * 256 + threadIdx.x;
    int d8 = i & 7;
    int s  = (i >> 3)  & (SEQ - 1);
    int h  = (i >> 14) & (HEADS - 1);
    int bb = (i >> 18) & 3;
    int kv = i >> 20;
    int col = (kv == 0 ? 2*D_MODEL : 0) + h*KD + d8*8;
    short8 v = *reinterpret_cast<const short8*>(
        qkv + (size_t)(bb*SEQ + s) * QKV_N + col);
    f32x4 lo, hi;
    #pragma unroll
    for (int j = 0; j < 4; ++j) {
        lo[j] = bf2f((unsigned short)v[j]);
        hi[j] = bf2f((unsigned short)v[j + 4]);
    }
    *reinterpret_cast<f32x4*>(pres + (size_t)i * 8)     = lo;
    *reinterpret_cast<f32x4*>(pres + (size_t)i * 8 + 4) = hi;
}

// ---------------------------------------------------------------------------
// Flash-style causal attention. 64 q-rows/block, 4 waves x 16 rows.
// K and pre-transposed V staged via global_load_lds (swizzled-source pattern),
// double-buffered, 1 barrier/iter. log2-domain softmax + defer-rescale.
// LDS exactly 40960 B -> 4 blocks/CU.
// ---------------------------------------------------------------------------
__global__ __launch_bounds__(256) void attn_kernel(
    const unsigned short* __restrict__ qkv,
    const unsigned short* __restrict__ vtg,
    unsigned short* __restrict__ aout)
{
    __shared__ unsigned short Kl[2][64*64];   // [key][d-chunk swz]
    __shared__ unsigned short Vl[2][64*64];   // [d][key-chunk swz]
    __shared__ unsigned short Pl[4][16*64];   // [q][key-chunk swz], per-wave

    const int tid  = threadIdx.x;
    const int lane = tid & 63;
    const int w    = tid >> 6;
    const int l15  = lane & 15, lg = lane >> 4;

    const int qt = blockIdx.x;
    const int h  = blockIdx.y;
    const int b  = blockIdx.z;
    const int q0 = qt * 64;

    const unsigned short* base  = qkv + (size_t)b * SEQ * QKV_N;
    const unsigned short* vbase = vtg + ((size_t)b * HEADS + h) * KD * SEQ;
    const int qoff = D_MODEL + h*KD;
    const int koff = 2*D_MODEL + h*KD;

    const int qrow = q0 + w*16 + l15;
    short8 aq0 = *reinterpret_cast<const short8*>(base + (size_t)qrow * QKV_N + qoff + lg*8);
    short8 aq1 = *reinterpret_cast<const short8*>(base + (size_t)qrow * QKV_N + qoff + 32 + lg*8);

    f32x4 o[4] = {{0,0,0,0},{0,0,0,0},{0,0,0,0},{0,0,0,0}};
    float mr[4] = {-1e30f, -1e30f, -1e30f, -1e30f};
    float sr[4] = {0.f, 0.f, 0.f, 0.f};

    const int ldrow = lane >> 3;   // 0..7
    const int slot  = lane & 7;
    const float SCALE2 = 0.125f * 1.44269504088896f;

    // prologue: stage tile 0
    #pragma unroll
    for (int i = 0; i < 2; ++i) {
        int kb = w*2 + i, row = kb*8 + ldrow, sc = slot ^ (row & 7);
        gload_lds16(&base[(size_t)row * QKV_N + koff + sc*8], &Kl[0][kb*512]);
        gload_lds16(&vbase[(size_t)row * SEQ + sc*8],         &Vl[0][kb*512]);
    }
    __syncthreads();

    for (int kt = 0; kt <= qt; ++kt) {
        const int buf = kt & 1;

        if (kt < qt) {   // prefetch next tile into other buffer (async, in flight over compute)
            #pragma unroll
            for (int i = 0; i < 2; ++i) {
                int kb = w*2 + i, row = kb*8 + ldrow, sc = slot ^ (row & 7);
                gload_lds16(&base[(size_t)((kt+1)*64 + row) * QKV_N + koff + sc*8],
                            &Kl[buf^1][kb*512]);
                gload_lds16(&vbase[(size_t)row * SEQ + (kt+1)*64 + sc*8],
                            &Vl[buf^1][kb*512]);
            }
        }

        // QK^T : 16(q) x 64(keys) per wave
        f32x4 s[4] = {{0,0,0,0},{0,0,0,0},{0,0,0,0},{0,0,0,0}};
        #pragma unroll
        for (int t = 0; t < 4; ++t) {
            int row = l15 + 16*t, sw = row & 7;
            short8 bk0 = *reinterpret_cast<const short8*>(&Kl[buf][row*64 + (lg       ^ sw)*8]);
            short8 bk1 = *reinterpret_cast<const short8*>(&Kl[buf][row*64 + ((lg + 4) ^ sw)*8]);
            s[t] = __builtin_amdgcn_mfma_f32_16x16x32_bf16(aq0, bk0, s[t], 0, 0, 0);
            s[t] = __builtin_amdgcn_mfma_f32_16x16x32_bf16(aq1, bk1, s[t], 0, 0, 0);
        }

        const bool diag = (kt == qt);
        float p[4][4];
        float lm[4] = {-1e30f, -1e30f, -1e30f, -1e30f};
        #pragma unroll
        for (int t = 0; t < 4; ++t) {
            #pragma unroll
            for (int r = 0; r < 4; ++r) {
                float sv = s[t][r] * SCALE2;
                if (diag) {
                    int rowl = w*16 + lg*4 + r;
                    int coll = l15 + 16*t;
                    if (coll > rowl) sv = -1e30f;
                }
                p[t][r] = sv;
                lm[r] = fmaxf(lm[r], sv);
            }
        }
        #pragma unroll
        for (int off = 1; off < 16; off <<= 1) {
            #pragma unroll
            for (int r = 0; r < 4; ++r) lm[r] = fmaxf(lm[r], __shfl_xor(lm[r], off, 64));
        }

        bool grow = (lm[0] > mr[0]) | (lm[1] > mr[1]) | (lm[2] > mr[2]) | (lm[3] > mr[3]);
        if (__any(grow)) {
            float fac[4];
            #pragma unroll
            for (int r = 0; r < 4; ++r) {
                float nm = fmaxf(mr[r], lm[r]);
                fac[r] = exp2f(mr[r] - nm);
                mr[r] = nm;
                sr[r] *= fac[r];
            }
            #pragma unroll
            for (int t2 = 0; t2 < 4; ++t2) {
                #pragma unroll
                for (int r = 0; r < 4; ++r) o[t2][r] *= fac[r];
            }
        }

        float tsum[4] = {0.f, 0.f, 0.f, 0.f};
        #pragma unroll
        for (int t = 0; t < 4; ++t) {
            #pragma unroll
            for (int r = 0; r < 4; ++r) {
                float pv = exp2f(p[t][r] - mr[r]);
                p[t][r] = pv;
                tsum[r] += pv;
            }
        }
        #pragma unroll
        for (int off = 1; off < 16; off <<= 1) {
            #pragma unroll
            for (int r = 0; r < 4; ++r) tsum[r] += __shfl_xor(tsum[r], off, 64);
        }
        #pragma unroll
        for (int r = 0; r < 4; ++r) sr[r] += tsum[r];

        // P -> wave-private swizzled LDS -> A-fragment layout
        #pragma unroll
        for (int t = 0; t < 4; ++t) {
            #pragma unroll
            for (int r = 0; r < 4; ++r) {
                int q   = lg*4 + r;
                int key = l15 + 16*t;
                Pl[w][q*64 + ((key >> 3) ^ (q & 7))*8 + (key & 7)] = f2bf(p[t][r]);
            }
        }
        short8 pa0 = *reinterpret_cast<const short8*>(&Pl[w][l15*64 + (lg       ^ (l15 & 7))*8]);
        short8 pa1 = *reinterpret_cast<const short8*>(&Pl[w][l15*64 + ((lg + 4) ^ (l15 & 7))*8]);

        #pragma unroll
        for (int t2 = 0; t2 < 4; ++t2) {
            int row = l15 + 16*t2, sw = row & 7;
            short8 bv0 = *reinterpret_cast<const short8*>(&Vl[buf][row*64 + (lg       ^ sw)*8]);
            short8 bv1 = *reinterpret_cast<const short8*>(&Vl[buf][row*64 + ((lg + 4) ^ sw)*8]);
            o[t2] = __builtin_amdgcn_mfma_f32_16x16x32_bf16(pa0, bv0, o[t2], 0, 0, 0);
            o[t2] = __builtin_amdgcn_mfma_f32_16x16x32_bf16(pa1, bv1, o[t2], 0, 0, 0);
        }

        __syncthreads();   // drains prefetch glds; all reads of buf complete
    }

    #pragma unroll
    for (int t2 = 0; t2 < 4; ++t2) {
        #pragma unroll
        for (int r = 0; r < 4; ++r) {
            int row = q0 + w*16 + lg*4 + r;
            aout[((size_t)b * SEQ + row) * D_MODEL + h*KD + l15 + 16*t2] =
                f2bf(o[t2][r] / sr[r]);
        }
    }
}

// ---------------------------------------------------------------------------
extern "C" void kernel_launch(void* const* d_in, const int* in_sizes, int n_in,
                              void* d_out, int out_size, void* d_ws, size_t ws_size,
                              hipStream_t stream)
{
    const float* x      = (const float*)d_in[0];
    const float* W_attn = (const float*)d_in[1];
    const float* b_attn = (const float*)d_in[2];
    const float* W_proj = (const float*)d_in[3];
    const float* b_proj = (const float*)d_in[4];
    float* out = (float*)d_out;

    unsigned short* qkv  = (unsigned short*)d_ws;                  // [8192][3072]
    unsigned short* xbf  = qkv + (size_t)NTOK * QKV_N;             // [8192][1024] (= aout later)
    unsigned short* aout = xbf;
    unsigned short* WT   = xbf + (size_t)NTOK * D_MODEL;           // [3072][1024]
    unsigned short* WpT  = WT + (size_t)QKV_N * D_MODEL;           // [1024][1024]
    unsigned short* vtg  = WpT + (size_t)D_MODEL * D_MODEL;        // [4][16][64][2048]

    cvt_kernel<<<(NTOK * D_MODEL / 8) / 256, 256, 0, stream>>>(x, xbf);
    dim3 gt1(QKV_N / 64, D_MODEL / 64);
    transpose_kernel<<<gt1, 256, 0, stream>>>(W_attn, WT, D_MODEL, QKV_N);
    dim3 gt2(D_MODEL / 64, D_MODEL / 64);
    transpose_kernel<<<gt2, 256, 0, stream>>>(W_proj, WpT, D_MODEL, D_MODEL);

    // qkv = x @ W_attn + b_attn   (+ fused transposed-V copy)
    dim3 g1(QKV_N / 128, NTOK / 128);
    gemm_bt_kernel<0, 1><<<g1, 256, 0, stream>>>(xbf, WT, b_attn, qkv, vtg,
                                                 NTOK, QKV_N, D_MODEL);

    // present = stack(k, v)
    present_kernel<<<(2 * BATCH * HEADS * SEQ * 8) / 256, 256, 0, stream>>>(
        qkv, out + (size_t)NTOK * D_MODEL);

    // causal attention
    dim3 ga(SEQ / 64, HEADS, BATCH);
    attn_kernel<<<ga, 256, 0, stream>>>(qkv, vtg, aout);

    // out = aout @ W_proj + b_proj
    dim3 g2(D_MODEL / 128, NTOK / 128);
    gemm_bt_kernel<1, 0><<<g2, 256, 0, stream>>>(aout, WpT, b_proj, out, nullptr,
                                                 NTOK, D_MODEL, D_MODEL);
}

// Round 5
// 281.566 us; speedup vs baseline: 2.4839x; 1.3066x over previous
//
#include <hip/hip_runtime.h>

typedef __attribute__((ext_vector_type(8))) short short8;
typedef __attribute__((ext_vector_type(4))) short short4v;
typedef __attribute__((ext_vector_type(4))) float f32x4;
typedef __attribute__((ext_vector_type(16))) float f32x16;
typedef __attribute__((ext_vector_type(4))) unsigned int u32x4;
typedef unsigned int u32;

#define D_MODEL 1024
#define HEADS 16
#define KD 64
#define SEQ 2048
#define BATCH 4
#define NTOK (BATCH*SEQ)    /* 8192 */
#define QKV_N (3*D_MODEL)   /* 3072 */

__device__ inline float bf2f(unsigned short u) {
    unsigned x = ((unsigned)u) << 16;
    return __builtin_bit_cast(float, x);
}
__device__ inline unsigned short f2bf(float f) {
    unsigned u = __builtin_bit_cast(unsigned, f);
    u += 0x7FFFu + ((u >> 16) & 1u);
    return (unsigned short)(u >> 16);
}
__device__ __forceinline__ void gload_lds16(const unsigned short* g, unsigned short* l) {
    __builtin_amdgcn_global_load_lds(
        (const __attribute__((address_space(1))) void*)g,
        (__attribute__((address_space(3))) void*)l, 16, 0, 0);
}
__device__ __forceinline__ u32 cvtpk(float lo, float hi) {
    u32 r; asm("v_cvt_pk_bf16_f32 %0, %1, %2" : "=v"(r) : "v"(lo), "v"(hi)); return r;
}

// ---------------------------------------------------------------------------
// x (f32) -> bf16, elementwise, 8 per thread
// ---------------------------------------------------------------------------
__global__ __launch_bounds__(256) void cvt_kernel(
    const float* __restrict__ x, unsigned short* __restrict__ y)
{
    size_t i = (size_t)blockIdx.x * 256 + threadIdx.x;
    f32x4 a = *reinterpret_cast<const f32x4*>(x + i*8);
    f32x4 b = *reinterpret_cast<const f32x4*>(x + i*8 + 4);
    short8 o;
    #pragma unroll
    for (int j = 0; j < 4; ++j) { o[j] = (short)f2bf(a[j]); o[j+4] = (short)f2bf(b[j]); }
    *reinterpret_cast<short8*>(y + i*8) = o;
}

// ---------------------------------------------------------------------------
// WT[n][k] = bf16(W[k][n]); tile 64x64 via LDS
// ---------------------------------------------------------------------------
__global__ __launch_bounds__(256) void transpose_kernel(
    const float* __restrict__ W, unsigned short* __restrict__ WT, int K, int N)
{
    __shared__ unsigned short T[64][80];
    const int tid = threadIdx.x;
    const int n0 = blockIdx.x * 64, k0 = blockIdx.y * 64;

    int r  = tid >> 2;
    int cq = tid & 3;
    const float* src = W + (size_t)(k0 + r) * N + n0 + cq*16;
    #pragma unroll
    for (int q = 0; q < 4; ++q) {
        f32x4 v = *reinterpret_cast<const f32x4*>(src + q*4);
        #pragma unroll
        for (int j = 0; j < 4; ++j) T[cq*16 + q*4 + j][r] = f2bf(v[j]);
    }
    __syncthreads();
    int c  = tid >> 2;
    int rq = tid & 3;
    short8 o0 = *reinterpret_cast<const short8*>(&T[c][rq*16]);
    short8 o1 = *reinterpret_cast<const short8*>(&T[c][rq*16 + 8]);
    unsigned short* dst = WT + (size_t)(n0 + c) * K + k0 + rq*16;
    *reinterpret_cast<short8*>(dst)     = o0;
    *reinterpret_cast<short8*>(dst + 8) = o1;
}

// ---------------------------------------------------------------------------
// Y = A[M,K](bf16) @ BT[N,K]^T(bf16) + bias(f32).  128x128 tile, BK=64,
// 4 waves (2x2), global_load_lds w/ pre-swizzled source, swizzled ds_read.
// VTG: for cols < D_MODEL also write vtg[b][h][d][s] (transposed V, bf16).
// ---------------------------------------------------------------------------
template<int Y_F32, int VTG>
__global__ __launch_bounds__(256) void gemm_bt_kernel(
    const unsigned short* __restrict__ A, const unsigned short* __restrict__ BT,
    const float* __restrict__ bias, void* __restrict__ Yv,
    unsigned short* __restrict__ vtg,
    int M, int N, int K)
{
    __shared__ unsigned short sA[128*64];
    __shared__ unsigned short sB[128*64];

    const int tid = threadIdx.x, lane = tid & 63, w = tid >> 6;
    const int l15 = lane & 15, lg = lane >> 4;
    const int n0 = blockIdx.x * 128, m0 = blockIdx.y * 128;
    const int wr = w >> 1, wc = w & 1;

    f32x4 acc[4][4];
    #pragma unroll
    for (int m = 0; m < 4; ++m)
        #pragma unroll
        for (int n = 0; n < 4; ++n) acc[m][n] = f32x4{0,0,0,0};

    const int ldrow = (lane >> 3);
    const int slot  = lane & 7;

    for (int k0 = 0; k0 < K; k0 += 64) {
        #pragma unroll
        for (int i = 0; i < 4; ++i) {
            int kb  = w*4 + i;
            int row = kb*8 + ldrow;
            int sc  = slot ^ (row & 7);
            gload_lds16(&A [(size_t)(m0 + row) * K + k0 + sc*8], &sA[kb*512]);
            gload_lds16(&BT[(size_t)(n0 + row) * K + k0 + sc*8], &sB[kb*512]);
        }
        __syncthreads();

        #pragma unroll
        for (int kk = 0; kk < 2; ++kk) {
            short8 af[4], bfr[4];
            #pragma unroll
            for (int m = 0; m < 4; ++m) {
                int row = wr*64 + m*16 + l15;
                int ch  = (4*kk + lg) ^ (row & 7);
                af[m] = *reinterpret_cast<const short8*>(&sA[row*64 + ch*8]);
            }
            #pragma unroll
            for (int n = 0; n < 4; ++n) {
                int row = wc*64 + n*16 + l15;
                int ch  = (4*kk + lg) ^ (row & 7);
                bfr[n] = *reinterpret_cast<const short8*>(&sB[row*64 + ch*8]);
            }
            #pragma unroll
            for (int m = 0; m < 4; ++m)
                #pragma unroll
                for (int n = 0; n < 4; ++n)
                    acc[m][n] = __builtin_amdgcn_mfma_f32_16x16x32_bf16(
                        af[m], bfr[n], acc[m][n], 0, 0, 0);
        }
        __syncthreads();
    }

    #pragma unroll
    for (int n = 0; n < 4; ++n) {
        int col = n0 + wc*64 + n*16 + l15;
        float bv = bias[col];
        #pragma unroll
        for (int m = 0; m < 4; ++m) {
            int row0 = m0 + wr*64 + m*16 + lg*4;
            float v0 = acc[m][n][0] + bv;
            float v1 = acc[m][n][1] + bv;
            float v2 = acc[m][n][2] + bv;
            float v3 = acc[m][n][3] + bv;
            if (Y_F32) {
                float* Y = (float*)Yv;
                Y[(size_t)(row0+0) * N + col] = v0;
                Y[(size_t)(row0+1) * N + col] = v1;
                Y[(size_t)(row0+2) * N + col] = v2;
                Y[(size_t)(row0+3) * N + col] = v3;
            } else {
                unsigned short* Y = (unsigned short*)Yv;
                Y[(size_t)(row0+0) * N + col] = f2bf(v0);
                Y[(size_t)(row0+1) * N + col] = f2bf(v1);
                Y[(size_t)(row0+2) * N + col] = f2bf(v2);
                Y[(size_t)(row0+3) * N + col] = f2bf(v3);
            }
            if (VTG && n0 < D_MODEL) {   // V columns: also write transposed copy
                int hh = col >> 6, dd = col & 63;
                int bb = row0 >> 11, ss = row0 & (SEQ - 1);
                short4v pk;
                pk[0] = (short)f2bf(v0); pk[1] = (short)f2bf(v1);
                pk[2] = (short)f2bf(v2); pk[3] = (short)f2bf(v3);
                *reinterpret_cast<short4v*>(
                    vtg + (((size_t)bb*HEADS + hh)*KD + dd)*SEQ + ss) = pk;
            }
        }
    }
}

// ---------------------------------------------------------------------------
// present[2,B,H,S,64] (f32): [0]=key (qkv col 2048+h*64), [1]=value (col h*64)
// ---------------------------------------------------------------------------
__global__ __launch_bounds__(256) void present_kernel(
    const unsigned short* __restrict__ qkv, float* __restrict__ pres)
{
    int i  = blockIdx.x * 256 + threadIdx.x;
    int d8 = i & 7;
    int s  = (i >> 3)  & (SEQ - 1);
    int h  = (i >> 14) & (HEADS - 1);
    int bb = (i >> 18) & 3;
    int kv = i >> 20;
    int col = (kv == 0 ? 2*D_MODEL : 0) + h*KD + d8*8;
    short8 v = *reinterpret_cast<const short8*>(
        qkv + (size_t)(bb*SEQ + s) * QKV_N + col);
    f32x4 lo, hi;
    #pragma unroll
    for (int j = 0; j < 4; ++j) {
        lo[j] = bf2f((unsigned short)v[j]);
        hi[j] = bf2f((unsigned short)v[j + 4]);
    }
    *reinterpret_cast<f32x4*>(pres + (size_t)i * 8)     = lo;
    *reinterpret_cast<f32x4*>(pres + (size_t)i * 8 + 4) = hi;
}

// ---------------------------------------------------------------------------
// Flash attention, swapped-operand 32x32 MFMA form.
// Block = 128 q-rows (4 waves x 32), KV staged 64 keys/iter (double-buffered).
// S^T = mfma(K, Q): lane owns q = lane&31, keys = crow(r,hi) (in-lane softmax).
// O^T = mfma(V^T, P^T): P^T via cvt_pk + shfl_xor(32); V^T from vtg.
// ---------------------------------------------------------------------------
__global__ __launch_bounds__(256) void attn_kernel(
    const unsigned short* __restrict__ qkv,
    const unsigned short* __restrict__ vtg,
    unsigned short* __restrict__ aout)
{
    __shared__ unsigned short Kl[2][64*64];   // [key][d-chunk swz]
    __shared__ unsigned short Vl[2][64*64];   // [d][key-chunk swz]

    const int tid  = threadIdx.x;
    const int lane = tid & 63;
    const int w    = tid >> 6;
    const int l31  = lane & 31, hi = lane >> 5;

    const int qb = blockIdx.x;   // 0..15
    const int h  = blockIdx.y;
    const int b  = blockIdx.z;
    const int q0 = qb * 128;

    const unsigned short* base  = qkv + (size_t)b * SEQ * QKV_N;
    const unsigned short* vbase = vtg + ((size_t)b * HEADS + h) * KD * SEQ;
    const int qoff = D_MODEL + h*KD;
    const int koff = 2*D_MODEL + h*KD;

    const int qrow  = q0 + w*32 + l31;   // this lane's q row
    const int qminw = q0 + w*32;

    // Q B-fragments: qf[ks] = Q[qrow][16ks + 8hi .. +7]
    short8 qf[4];
    #pragma unroll
    for (int ks = 0; ks < 4; ++ks)
        qf[ks] = *reinterpret_cast<const short8*>(
            base + (size_t)qrow * QKV_N + qoff + ks*16 + hi*8);

    f32x16 o0, o1;
    #pragma unroll
    for (int r = 0; r < 16; ++r) { o0[r] = 0.f; o1[r] = 0.f; }
    float m = -1e30f, msc = -1e30f * 0.180336887f, sr = 0.f;

    const float SCALE2 = 0.125f * 1.44269504088896f;   // 0.18034
    const float THR_RAW = 44.36f;                      // 8 / SCALE2

    const int ldrow = lane >> 3;
    const int slot  = lane & 7;
    const int nt = q0/64 + 2;   // staged 64-key tiles

    // prologue: stage tile 0
    #pragma unroll
    for (int i = 0; i < 2; ++i) {
        int kb = w*2 + i, row = kb*8 + ldrow, sc = slot ^ (row & 7);
        gload_lds16(&base[(size_t)row * QKV_N + koff + sc*8], &Kl[0][kb*512]);
        gload_lds16(&vbase[(size_t)row * SEQ + sc*8],         &Vl[0][kb*512]);
    }
    __syncthreads();

    for (int t = 0; t < nt; ++t) {
        const int buf = t & 1;

        if (t + 1 < nt) {   // prefetch next tile (async over compute)
            #pragma unroll
            for (int i = 0; i < 2; ++i) {
                int kb = w*2 + i, row = kb*8 + ldrow, sc = slot ^ (row & 7);
                gload_lds16(&base[(size_t)((t+1)*64 + row) * QKV_N + koff + sc*8],
                            &Kl[buf^1][kb*512]);
                gload_lds16(&vbase[(size_t)row * SEQ + (t+1)*64 + sc*8],
                            &Vl[buf^1][kb*512]);
            }
        }

        #pragma unroll
        for (int h32 = 0; h32 < 2; ++h32) {
            const int kb0 = t*64 + h32*32;
            if (kb0 < qminw + 32) {    // else: wave fully past diagonal, skip
                // ---- QK^T (S^T tile [32 keys][32 q]) ----
                f32x16 s;
                #pragma unroll
                for (int r = 0; r < 16; ++r) s[r] = 0.f;
                const int krow = h32*32 + l31;
                const int ksw  = krow & 7;
                #pragma unroll
                for (int ks = 0; ks < 4; ++ks) {
                    short8 kf = *reinterpret_cast<const short8*>(
                        &Kl[buf][krow*64 + ((2*ks + hi) ^ ksw)*8]);
                    s = __builtin_amdgcn_mfma_f32_32x32x16_bf16(kf, qf[ks], s, 0, 0, 0);
                }

                if (kb0 == qminw) {   // diagonal tile: mask key > q
                    const int kq = l31 - 4*hi;
                    #pragma unroll
                    for (int r = 0; r < 16; ++r) {
                        const int cr = (r & 3) + 8*(r >> 2);
                        s[r] = (cr <= kq) ? s[r] : -1e30f;
                    }
                }

                // ---- in-lane max + defer-rescale ----
                float pm = s[0];
                #pragma unroll
                for (int r = 1; r < 16; ++r) pm = fmaxf(pm, s[r]);
                pm = fmaxf(pm, __shfl_xor(pm, 32, 64));
                if (!__all(pm <= m + THR_RAW)) {
                    float mn  = fmaxf(m, pm);
                    float fac = exp2f((m - mn) * SCALE2);
                    sr *= fac;
                    #pragma unroll
                    for (int r = 0; r < 16; ++r) { o0[r] *= fac; o1[r] *= fac; }
                    m = mn; msc = m * SCALE2;
                }

                // ---- exp + sum (in-lane) ----
                float ts = 0.f;
                #pragma unroll
                for (int r = 0; r < 16; ++r) {
                    float pv = exp2f(s[r]*SCALE2 - msc);
                    s[r] = pv;
                    ts += pv;
                }
                sr += ts + __shfl_xor(ts, 32, 64);

                // ---- pack P to bf16 words ----
                u32 W[8];
                #pragma unroll
                for (int wi = 0; wi < 8; ++wi) W[wi] = cvtpk(s[2*wi], s[2*wi+1]);

                // ---- PV: O^T += V^T @ P^T ----
                #pragma unroll
                for (int ks = 0; ks < 2; ++ks) {
                    u32 s0 = hi ? W[4*ks+0] : W[4*ks+2];
                    u32 s1 = hi ? W[4*ks+1] : W[4*ks+3];
                    u32 r0 = (u32)__shfl_xor((int)s0, 32, 64);
                    u32 r1 = (u32)__shfl_xor((int)s1, 32, 64);
                    u32x4 wv;
                    wv[0] = hi ? r0 : W[4*ks+0];
                    wv[1] = hi ? r1 : W[4*ks+1];
                    wv[2] = hi ? W[4*ks+2] : r0;
                    wv[3] = hi ? W[4*ks+3] : r1;
                    short8 pfrag = __builtin_bit_cast(short8, wv);
                    #pragma unroll
                    for (int dt = 0; dt < 2; ++dt) {
                        const int vrow = dt*32 + l31;
                        const int vch  = (4*h32 + 2*ks + hi) ^ (vrow & 7);
                        short8 vf = *reinterpret_cast<const short8*>(
                            &Vl[buf][vrow*64 + vch*8]);
                        if (dt == 0)
                            o0 = __builtin_amdgcn_mfma_f32_32x32x16_bf16(vf, pfrag, o0, 0, 0, 0);
                        else
                            o1 = __builtin_amdgcn_mfma_f32_32x32x16_bf16(vf, pfrag, o1, 0, 0, 0);
                    }
                }
            }
        }
        __syncthreads();
    }

    // ---- epilogue: out[qrow][d] = o[d]/sr  (d = crow(reg,hi) + 32*dt) ----
    const float inv = 1.0f / sr;
    unsigned short* orow = aout + ((size_t)b * SEQ + qrow) * D_MODEL + h*KD;
    #pragma unroll
    for (int dt = 0; dt < 2; ++dt) {
        #pragma unroll
        for (int g = 0; g < 4; ++g) {
            short4v pk;
            #pragma unroll
            for (int j = 0; j < 4; ++j) {
                float v = (dt == 0 ? o0[4*g + j] : o1[4*g + j]) * inv;
                pk[j] = (short)f2bf(v);
            }
            *reinterpret_cast<short4v*>(orow + dt*32 + 8*g + 4*hi) = pk;
        }
    }
}

// ---------------------------------------------------------------------------
extern "C" void kernel_launch(void* const* d_in, const int* in_sizes, int n_in,
                              void* d_out, int out_size, void* d_ws, size_t ws_size,
                              hipStream_t stream)
{
    const float* x      = (const float*)d_in[0];
    const float* W_attn = (const float*)d_in[1];
    const float* b_attn = (const float*)d_in[2];
    const float* W_proj = (const float*)d_in[3];
    const float* b_proj = (const float*)d_in[4];
    float* out = (float*)d_out;

    unsigned short* qkv  = (unsigned short*)d_ws;                  // [8192][3072]
    unsigned short* xbf  = qkv + (size_t)NTOK * QKV_N;             // [8192][1024] (= aout later)
    unsigned short* aout = xbf;
    unsigned short* WT   = xbf + (size_t)NTOK * D_MODEL;           // [3072][1024]
    unsigned short* WpT  = WT + (size_t)QKV_N * D_MODEL;           // [1024][1024]
    unsigned short* vtg  = WpT + (size_t)D_MODEL * D_MODEL;        // [4][16][64][2048]

    cvt_kernel<<<(NTOK * D_MODEL / 8) / 256, 256, 0, stream>>>(x, xbf);
    dim3 gt1(QKV_N / 64, D_MODEL / 64);
    transpose_kernel<<<gt1, 256, 0, stream>>>(W_attn, WT, D_MODEL, QKV_N);
    dim3 gt2(D_MODEL / 64, D_MODEL / 64);
    transpose_kernel<<<gt2, 256, 0, stream>>>(W_proj, WpT, D_MODEL, D_MODEL);

    // qkv = x @ W_attn + b_attn   (+ fused transposed-V copy)
    dim3 g1(QKV_N / 128, NTOK / 128);
    gemm_bt_kernel<0, 1><<<g1, 256, 0, stream>>>(xbf, WT, b_attn, qkv, vtg,
                                                 NTOK, QKV_N, D_MODEL);

    // present = stack(k, v)
    present_kernel<<<(2 * BATCH * HEADS * SEQ * 8) / 256, 256, 0, stream>>>(
        qkv, out + (size_t)NTOK * D_MODEL);

    // causal attention (swapped-operand form)
    dim3 ga(SEQ / 128, HEADS, BATCH);
    attn_kernel<<<ga, 256, 0, stream>>>(qkv, vtg, aout);

    // out = aout @ W_proj + b_proj
    dim3 g2(D_MODEL / 128, NTOK / 128);
    gemm_bt_kernel<1, 0><<<g2, 256, 0, stream>>>(aout, WpT, b_proj, out, nullptr,
                                                 NTOK, D_MODEL, D_MODEL);
}

// Round 6
// 219.163 us; speedup vs baseline: 3.1912x; 1.2847x over previous
//
#include <hip/hip_runtime.h>

typedef __attribute__((ext_vector_type(8))) short short8;
typedef __attribute__((ext_vector_type(4))) short short4v;
typedef __attribute__((ext_vector_type(4))) float f32x4;
typedef __attribute__((ext_vector_type(16))) float f32x16;
typedef __attribute__((ext_vector_type(4))) unsigned int u32x4;
typedef unsigned int u32;

#define D_MODEL 1024
#define HEADS 16
#define KD 64
#define SEQ 2048
#define BATCH 4
#define NTOK (BATCH*SEQ)    /* 8192 */
#define QKV_N (3*D_MODEL)   /* 3072 */

__device__ inline float bf2f(unsigned short u) {
    unsigned x = ((unsigned)u) << 16;
    return __builtin_bit_cast(float, x);
}
__device__ inline unsigned short f2bf(float f) {
    unsigned u = __builtin_bit_cast(unsigned, f);
    u += 0x7FFFu + ((u >> 16) & 1u);
    return (unsigned short)(u >> 16);
}
__device__ __forceinline__ void gload_lds16(const unsigned short* g, unsigned short* l) {
    __builtin_amdgcn_global_load_lds(
        (const __attribute__((address_space(1))) void*)g,
        (__attribute__((address_space(3))) void*)l, 16, 0, 0);
}
__device__ __forceinline__ u32 cvtpk(float lo, float hi) {
    u32 r; asm("v_cvt_pk_bf16_f32 %0, %1, %2" : "=v"(r) : "v"(lo), "v"(hi)); return r;
}

// ---------------------------------------------------------------------------
// x (f32) -> bf16, elementwise, 8 per thread
// ---------------------------------------------------------------------------
__global__ __launch_bounds__(256) void cvt_kernel(
    const float* __restrict__ x, unsigned short* __restrict__ y)
{
    size_t i = (size_t)blockIdx.x * 256 + threadIdx.x;
    f32x4 a = *reinterpret_cast<const f32x4*>(x + i*8);
    f32x4 b = *reinterpret_cast<const f32x4*>(x + i*8 + 4);
    short8 o;
    #pragma unroll
    for (int j = 0; j < 4; ++j) { o[j] = (short)f2bf(a[j]); o[j+4] = (short)f2bf(b[j]); }
    *reinterpret_cast<short8*>(y + i*8) = o;
}

// ---------------------------------------------------------------------------
// WT[n][k] = bf16(W[k][n]); tile 64x64 via LDS
// ---------------------------------------------------------------------------
__global__ __launch_bounds__(256) void transpose_kernel(
    const float* __restrict__ W, unsigned short* __restrict__ WT, int K, int N)
{
    __shared__ unsigned short T[64][80];
    const int tid = threadIdx.x;
    const int n0 = blockIdx.x * 64, k0 = blockIdx.y * 64;

    int r  = tid >> 2;
    int cq = tid & 3;
    const float* src = W + (size_t)(k0 + r) * N + n0 + cq*16;
    #pragma unroll
    for (int q = 0; q < 4; ++q) {
        f32x4 v = *reinterpret_cast<const f32x4*>(src + q*4);
        #pragma unroll
        for (int j = 0; j < 4; ++j) T[cq*16 + q*4 + j][r] = f2bf(v[j]);
    }
    __syncthreads();
    int c  = tid >> 2;
    int rq = tid & 3;
    short8 o0 = *reinterpret_cast<const short8*>(&T[c][rq*16]);
    short8 o1 = *reinterpret_cast<const short8*>(&T[c][rq*16 + 8]);
    unsigned short* dst = WT + (size_t)(n0 + c) * K + k0 + rq*16;
    *reinterpret_cast<short8*>(dst)     = o0;
    *reinterpret_cast<short8*>(dst + 8) = o1;
}

// ---------------------------------------------------------------------------
// Y = A[M,K](bf16) @ BT[N,K]^T(bf16) + bias(f32).  128x128 tile, BK=64,
// 4 waves (2x2), global_load_lds w/ pre-swizzled source, swizzled ds_read.
// XCD-aware bijective block swizzle (requires nwg % 8 == 0).
// VTG: for cols < D_MODEL also write vtg[b][h][d][s] (transposed V, bf16).
// ---------------------------------------------------------------------------
template<int Y_F32, int VTG>
__global__ __launch_bounds__(256) void gemm_bt_kernel(
    const unsigned short* __restrict__ A, const unsigned short* __restrict__ BT,
    const float* __restrict__ bias, void* __restrict__ Yv,
    unsigned short* __restrict__ vtg,
    int M, int N, int K)
{
    __shared__ unsigned short sA[128*64];
    __shared__ unsigned short sB[128*64];

    const int tid = threadIdx.x, lane = tid & 63, w = tid >> 6;
    const int l15 = lane & 15, lg = lane >> 4;

    // XCD-aware swizzle: bid -> (bid%8)*(nwg/8) + bid/8
    const int nwg = gridDim.x * gridDim.y;
    const int bid = blockIdx.y * gridDim.x + blockIdx.x;
    const int swz = (bid & 7) * (nwg >> 3) + (bid >> 3);
    const int n0 = (swz % gridDim.x) * 128;
    const int m0 = (swz / gridDim.x) * 128;

    const int wr = w >> 1, wc = w & 1;

    f32x4 acc[4][4];
    #pragma unroll
    for (int m = 0; m < 4; ++m)
        #pragma unroll
        for (int n = 0; n < 4; ++n) acc[m][n] = f32x4{0,0,0,0};

    const int ldrow = (lane >> 3);
    const int slot  = lane & 7;

    for (int k0 = 0; k0 < K; k0 += 64) {
        #pragma unroll
        for (int i = 0; i < 4; ++i) {
            int kb  = w*4 + i;
            int row = kb*8 + ldrow;
            int sc  = slot ^ (row & 7);
            gload_lds16(&A [(size_t)(m0 + row) * K + k0 + sc*8], &sA[kb*512]);
            gload_lds16(&BT[(size_t)(n0 + row) * K + k0 + sc*8], &sB[kb*512]);
        }
        __syncthreads();

        #pragma unroll
        for (int kk = 0; kk < 2; ++kk) {
            short8 af[4], bfr[4];
            #pragma unroll
            for (int m = 0; m < 4; ++m) {
                int row = wr*64 + m*16 + l15;
                int ch  = (4*kk + lg) ^ (row & 7);
                af[m] = *reinterpret_cast<const short8*>(&sA[row*64 + ch*8]);
            }
            #pragma unroll
            for (int n = 0; n < 4; ++n) {
                int row = wc*64 + n*16 + l15;
                int ch  = (4*kk + lg) ^ (row & 7);
                bfr[n] = *reinterpret_cast<const short8*>(&sB[row*64 + ch*8]);
            }
            __builtin_amdgcn_s_setprio(1);
            #pragma unroll
            for (int m = 0; m < 4; ++m)
                #pragma unroll
                for (int n = 0; n < 4; ++n)
                    acc[m][n] = __builtin_amdgcn_mfma_f32_16x16x32_bf16(
                        af[m], bfr[n], acc[m][n], 0, 0, 0);
            __builtin_amdgcn_s_setprio(0);
        }
        __syncthreads();
    }

    #pragma unroll
    for (int n = 0; n < 4; ++n) {
        int col = n0 + wc*64 + n*16 + l15;
        float bv = bias[col];
        #pragma unroll
        for (int m = 0; m < 4; ++m) {
            int row0 = m0 + wr*64 + m*16 + lg*4;
            float v0 = acc[m][n][0] + bv;
            float v1 = acc[m][n][1] + bv;
            float v2 = acc[m][n][2] + bv;
            float v3 = acc[m][n][3] + bv;
            if (Y_F32) {
                float* Y = (float*)Yv;
                Y[(size_t)(row0+0) * N + col] = v0;
                Y[(size_t)(row0+1) * N + col] = v1;
                Y[(size_t)(row0+2) * N + col] = v2;
                Y[(size_t)(row0+3) * N + col] = v3;
            } else {
                unsigned short* Y = (unsigned short*)Yv;
                Y[(size_t)(row0+0) * N + col] = f2bf(v0);
                Y[(size_t)(row0+1) * N + col] = f2bf(v1);
                Y[(size_t)(row0+2) * N + col] = f2bf(v2);
                Y[(size_t)(row0+3) * N + col] = f2bf(v3);
            }
            if (VTG && n0 < D_MODEL) {   // V columns: also write transposed copy
                int hh = col >> 6, dd = col & 63;
                int bb = row0 >> 11, ss = row0 & (SEQ - 1);
                short4v pk;
                pk[0] = (short)f2bf(v0); pk[1] = (short)f2bf(v1);
                pk[2] = (short)f2bf(v2); pk[3] = (short)f2bf(v3);
                *reinterpret_cast<short4v*>(
                    vtg + (((size_t)bb*HEADS + hh)*KD + dd)*SEQ + ss) = pk;
            }
        }
    }
}

// ---------------------------------------------------------------------------
// present[2,B,H,S,64] (f32): [0]=key (qkv col 2048+h*64), [1]=value (col h*64)
// ---------------------------------------------------------------------------
__global__ __launch_bounds__(256) void present_kernel(
    const unsigned short* __restrict__ qkv, float* __restrict__ pres)
{
    int i  = blockIdx.x * 256 + threadIdx.x;
    int d8 = i & 7;
    int s  = (i >> 3)  & (SEQ - 1);
    int h  = (i >> 14) & (HEADS - 1);
    int bb = (i >> 18) & 3;
    int kv = i >> 20;
    int col = (kv == 0 ? 2*D_MODEL : 0) + h*KD + d8*8;
    short8 v = *reinterpret_cast<const short8*>(
        qkv + (size_t)(bb*SEQ + s) * QKV_N + col);
    f32x4 lo, hi;
    #pragma unroll
    for (int j = 0; j < 4; ++j) {
        lo[j] = bf2f((unsigned short)v[j]);
        hi[j] = bf2f((unsigned short)v[j + 4]);
    }
    *reinterpret_cast<f32x4*>(pres + (size_t)i * 8)     = lo;
    *reinterpret_cast<f32x4*>(pres + (size_t)i * 8 + 4) = hi;
}

// ---------------------------------------------------------------------------
// Flash attention, swapped-operand 32x32 MFMA form, work-balanced:
// block = (qpair, h, b) processes q-tiles qb=qpair and qb=15-qpair
// sequentially -> every block does exactly 34 staged tile-iters.
// S^T = mfma(K, Q): lane owns q = lane&31 (in-lane softmax).
// O^T = mfma(V^T, P^T): P^T via cvt_pk + shfl_xor(32); V^T from vtg.
// ---------------------------------------------------------------------------
__global__ __launch_bounds__(256) void attn_kernel(
    const unsigned short* __restrict__ qkv,
    const unsigned short* __restrict__ vtg,
    unsigned short* __restrict__ aout)
{
    __shared__ unsigned short Kl[2][64*64];   // [key][d-chunk swz]
    __shared__ unsigned short Vl[2][64*64];   // [d][key-chunk swz]

    const int tid  = threadIdx.x;
    const int lane = tid & 63;
    const int w    = tid >> 6;
    const int l31  = lane & 31, hi = lane >> 5;

    const int qpair = blockIdx.x;   // 0..7
    const int h  = blockIdx.y;
    const int b  = blockIdx.z;

    const unsigned short* base  = qkv + (size_t)b * SEQ * QKV_N;
    const unsigned short* vbase = vtg + ((size_t)b * HEADS + h) * KD * SEQ;
    const int qoff = D_MODEL + h*KD;
    const int koff = 2*D_MODEL + h*KD;

    const float SCALE2 = 0.125f * 1.44269504088896f;   // 0.18034
    const float THR_RAW = 44.36f;                      // 8 / SCALE2

    const int ldrow = lane >> 3;
    const int slot  = lane & 7;

    for (int pass = 0; pass < 2; ++pass) {
        const int qb = pass ? (15 - qpair) : qpair;
        const int q0 = qb * 128;
        const int qrow  = q0 + w*32 + l31;
        const int qminw = q0 + w*32;

        short8 qf[4];
        #pragma unroll
        for (int ks = 0; ks < 4; ++ks)
            qf[ks] = *reinterpret_cast<const short8*>(
                base + (size_t)qrow * QKV_N + qoff + ks*16 + hi*8);

        f32x16 o0, o1;
        #pragma unroll
        for (int r = 0; r < 16; ++r) { o0[r] = 0.f; o1[r] = 0.f; }
        float m = -1e30f, msc = -1e30f * 0.180336887f, sr = 0.f;

        const int nt = q0/64 + 2;

        // prologue: stage tile 0
        #pragma unroll
        for (int i = 0; i < 2; ++i) {
            int kb = w*2 + i, row = kb*8 + ldrow, sc = slot ^ (row & 7);
            gload_lds16(&base[(size_t)row * QKV_N + koff + sc*8], &Kl[0][kb*512]);
            gload_lds16(&vbase[(size_t)row * SEQ + sc*8],         &Vl[0][kb*512]);
        }
        __syncthreads();

        for (int t = 0; t < nt; ++t) {
            const int buf = t & 1;

            if (t + 1 < nt) {   // prefetch next tile (async over compute)
                #pragma unroll
                for (int i = 0; i < 2; ++i) {
                    int kb = w*2 + i, row = kb*8 + ldrow, sc = slot ^ (row & 7);
                    gload_lds16(&base[(size_t)((t+1)*64 + row) * QKV_N + koff + sc*8],
                                &Kl[buf^1][kb*512]);
                    gload_lds16(&vbase[(size_t)row * SEQ + (t+1)*64 + sc*8],
                                &Vl[buf^1][kb*512]);
                }
            }

            #pragma unroll
            for (int h32 = 0; h32 < 2; ++h32) {
                const int kb0 = t*64 + h32*32;
                if (kb0 < qminw + 32) {    // else: wave fully past diagonal
                    // ---- QK^T (S^T tile [32 keys][32 q]) ----
                    f32x16 s;
                    #pragma unroll
                    for (int r = 0; r < 16; ++r) s[r] = 0.f;
                    const int krow = h32*32 + l31;
                    const int ksw  = krow & 7;
                    __builtin_amdgcn_s_setprio(1);
                    #pragma unroll
                    for (int ks = 0; ks < 4; ++ks) {
                        short8 kf = *reinterpret_cast<const short8*>(
                            &Kl[buf][krow*64 + ((2*ks + hi) ^ ksw)*8]);
                        s = __builtin_amdgcn_mfma_f32_32x32x16_bf16(kf, qf[ks], s, 0, 0, 0);
                    }
                    __builtin_amdgcn_s_setprio(0);

                    if (kb0 == qminw) {   // diagonal tile: mask key > q
                        const int kq = l31 - 4*hi;
                        #pragma unroll
                        for (int r = 0; r < 16; ++r) {
                            const int cr = (r & 3) + 8*(r >> 2);
                            s[r] = (cr <= kq) ? s[r] : -1e30f;
                        }
                    }

                    // ---- in-lane max + defer-rescale ----
                    float pm = s[0];
                    #pragma unroll
                    for (int r = 1; r < 16; ++r) pm = fmaxf(pm, s[r]);
                    pm = fmaxf(pm, __shfl_xor(pm, 32, 64));
                    if (!__all(pm <= m + THR_RAW)) {
                        float mn  = fmaxf(m, pm);
                        float fac = exp2f((m - mn) * SCALE2);
                        sr *= fac;
                        #pragma unroll
                        for (int r = 0; r < 16; ++r) { o0[r] *= fac; o1[r] *= fac; }
                        m = mn; msc = m * SCALE2;
                    }

                    // ---- exp + sum (in-lane) ----
                    float ts = 0.f;
                    #pragma unroll
                    for (int r = 0; r < 16; ++r) {
                        float pv = exp2f(s[r]*SCALE2 - msc);
                        s[r] = pv;
                        ts += pv;
                    }
                    sr += ts + __shfl_xor(ts, 32, 64);

                    // ---- pack P to bf16 words ----
                    u32 W[8];
                    #pragma unroll
                    for (int wi = 0; wi < 8; ++wi) W[wi] = cvtpk(s[2*wi], s[2*wi+1]);

                    // ---- PV: O^T += V^T @ P^T ----
                    #pragma unroll
                    for (int ks = 0; ks < 2; ++ks) {
                        u32 s0 = hi ? W[4*ks+0] : W[4*ks+2];
                        u32 s1 = hi ? W[4*ks+1] : W[4*ks+3];
                        u32 r0 = (u32)__shfl_xor((int)s0, 32, 64);
                        u32 r1 = (u32)__shfl_xor((int)s1, 32, 64);
                        u32x4 wv;
                        wv[0] = hi ? r0 : W[4*ks+0];
                        wv[1] = hi ? r1 : W[4*ks+1];
                        wv[2] = hi ? W[4*ks+2] : r0;
                        wv[3] = hi ? W[4*ks+3] : r1;
                        short8 pfrag = __builtin_bit_cast(short8, wv);
                        __builtin_amdgcn_s_setprio(1);
                        #pragma unroll
                        for (int dt = 0; dt < 2; ++dt) {
                            const int vrow = dt*32 + l31;
                            const int vch  = (4*h32 + 2*ks + hi) ^ (vrow & 7);
                            short8 vf = *reinterpret_cast<const short8*>(
                                &Vl[buf][vrow*64 + vch*8]);
                            if (dt == 0)
                                o0 = __builtin_amdgcn_mfma_f32_32x32x16_bf16(vf, pfrag, o0, 0, 0, 0);
                            else
                                o1 = __builtin_amdgcn_mfma_f32_32x32x16_bf16(vf, pfrag, o1, 0, 0, 0);
                        }
                        __builtin_amdgcn_s_setprio(0);
                    }
                }
            }
            __syncthreads();
        }

        // ---- epilogue: out[qrow][d] = o[d]/sr ----
        const float inv = 1.0f / sr;
        unsigned short* orow = aout + ((size_t)b * SEQ + qrow) * D_MODEL + h*KD;
        #pragma unroll
        for (int dt = 0; dt < 2; ++dt) {
            #pragma unroll
            for (int g = 0; g < 4; ++g) {
                short4v pk;
                #pragma unroll
                for (int j = 0; j < 4; ++j) {
                    float v = (dt == 0 ? o0[4*g + j] : o1[4*g + j]) * inv;
                    pk[j] = (short)f2bf(v);
                }
                *reinterpret_cast<short4v*>(orow + dt*32 + 8*g + 4*hi) = pk;
            }
        }
    }
}

// ---------------------------------------------------------------------------
extern "C" void kernel_launch(void* const* d_in, const int* in_sizes, int n_in,
                              void* d_out, int out_size, void* d_ws, size_t ws_size,
                              hipStream_t stream)
{
    const float* x      = (const float*)d_in[0];
    const float* W_attn = (const float*)d_in[1];
    const float* b_attn = (const float*)d_in[2];
    const float* W_proj = (const float*)d_in[3];
    const float* b_proj = (const float*)d_in[4];
    float* out = (float*)d_out;

    unsigned short* qkv  = (unsigned short*)d_ws;                  // [8192][3072]
    unsigned short* xbf  = qkv + (size_t)NTOK * QKV_N;             // [8192][1024] (= aout later)
    unsigned short* aout = xbf;
    unsigned short* WT   = xbf + (size_t)NTOK * D_MODEL;           // [3072][1024]
    unsigned short* WpT  = WT + (size_t)QKV_N * D_MODEL;           // [1024][1024]
    unsigned short* vtg  = WpT + (size_t)D_MODEL * D_MODEL;        // [4][16][64][2048]

    cvt_kernel<<<(NTOK * D_MODEL / 8) / 256, 256, 0, stream>>>(x, xbf);
    dim3 gt1(QKV_N / 64, D_MODEL / 64);
    transpose_kernel<<<gt1, 256, 0, stream>>>(W_attn, WT, D_MODEL, QKV_N);
    dim3 gt2(D_MODEL / 64, D_MODEL / 64);
    transpose_kernel<<<gt2, 256, 0, stream>>>(W_proj, WpT, D_MODEL, D_MODEL);

    // qkv = x @ W_attn + b_attn   (+ fused transposed-V copy)
    dim3 g1(QKV_N / 128, NTOK / 128);
    gemm_bt_kernel<0, 1><<<g1, 256, 0, stream>>>(xbf, WT, b_attn, qkv, vtg,
                                                 NTOK, QKV_N, D_MODEL);

    // present = stack(k, v)
    present_kernel<<<(2 * BATCH * HEADS * SEQ * 8) / 256, 256, 0, stream>>>(
        qkv, out + (size_t)NTOK * D_MODEL);

    // causal attention (swapped-operand, work-balanced)
    dim3 ga(SEQ / 256, HEADS, BATCH);
    attn_kernel<<<ga, 256, 0, stream>>>(qkv, vtg, aout);

    // out = aout @ W_proj + b_proj
    dim3 g2(D_MODEL / 128, NTOK / 128);
    gemm_bt_kernel<1, 0><<<g2, 256, 0, stream>>>(aout, WpT, b_proj, out, nullptr,
                                                 NTOK, D_MODEL, D_MODEL);
}

// Round 8
// 216.658 us; speedup vs baseline: 3.2281x; 1.0116x over previous
//
#include <hip/hip_runtime.h>

typedef __attribute__((ext_vector_type(8))) short short8;
typedef __attribute__((ext_vector_type(4))) short short4v;
typedef __attribute__((ext_vector_type(4))) float f32x4;
typedef __attribute__((ext_vector_type(16))) float f32x16;
typedef __attribute__((ext_vector_type(4))) unsigned int u32x4;
typedef __attribute__((ext_vector_type(2))) unsigned int u32x2;
typedef unsigned int u32;

#define D_MODEL 1024
#define HEADS 16
#define KD 64
#define SEQ 2048
#define BATCH 4
#define NTOK (BATCH*SEQ)    /* 8192 */
#define QKV_N (3*D_MODEL)   /* 3072 */

__device__ inline float bf2f(unsigned short u) {
    unsigned x = ((unsigned)u) << 16;
    return __builtin_bit_cast(float, x);
}
__device__ inline unsigned short f2bf(float f) {
    unsigned u = __builtin_bit_cast(unsigned, f);
    u += 0x7FFFu + ((u >> 16) & 1u);
    return (unsigned short)(u >> 16);
}
__device__ __forceinline__ void gload_lds16(const unsigned short* g, unsigned short* l) {
    __builtin_amdgcn_global_load_lds(
        (const __attribute__((address_space(1))) void*)g,
        (__attribute__((address_space(3))) void*)l, 16, 0, 0);
}
__device__ __forceinline__ u32 cvtpk(float lo, float hi) {
    u32 r; asm("v_cvt_pk_bf16_f32 %0, %1, %2" : "=v"(r) : "v"(lo), "v"(hi)); return r;
}
// Half-exchange across the lane<32 / lane>=32 split. After pl32swap(a,b),
// each lane's {a,b} is a permutation of {own value, partner-lane value}.
__device__ __forceinline__ void pl32swap(u32& a, u32& b) {
#if __has_builtin(__builtin_amdgcn_permlane32_swap)
    u32x2 r = __builtin_amdgcn_permlane32_swap(a, b, 0, 0);
    a = r[0]; b = r[1];
#else
    u32 pa = (u32)__shfl_xor((int)a, 32, 64);
    u32 pb = (u32)__shfl_xor((int)b, 32, 64);
    bool hb = (threadIdx.x & 32) != 0;
    u32 na = hb ? pb : a;
    u32 nb = hb ? b : pa;
    a = na; b = nb;
#endif
}
// Order-robust reductions: correct for any half-exchange return convention.
__device__ __forceinline__ float pairmax(float x) {
    u32 a = __builtin_bit_cast(u32, x), b = a;
    pl32swap(a, b);
    return fmaxf(x, fmaxf(__builtin_bit_cast(float, a), __builtin_bit_cast(float, b)));
}
__device__ __forceinline__ float pairsum(float x) {
    u32 a = __builtin_bit_cast(u32, x), b = a;
    pl32swap(a, b);
    return __builtin_bit_cast(float, a) + __builtin_bit_cast(float, b);
}

// ---------------------------------------------------------------------------
// x (f32) -> bf16, elementwise, 8 per thread
// ---------------------------------------------------------------------------
__global__ __launch_bounds__(256) void cvt_kernel(
    const float* __restrict__ x, unsigned short* __restrict__ y)
{
    size_t i = (size_t)blockIdx.x * 256 + threadIdx.x;
    f32x4 a = *reinterpret_cast<const f32x4*>(x + i*8);
    f32x4 b = *reinterpret_cast<const f32x4*>(x + i*8 + 4);
    short8 o;
    #pragma unroll
    for (int j = 0; j < 4; ++j) { o[j] = (short)f2bf(a[j]); o[j+4] = (short)f2bf(b[j]); }
    *reinterpret_cast<short8*>(y + i*8) = o;
}

// ---------------------------------------------------------------------------
// WT[n][k] = bf16(W[k][n]); tile 64x64 via LDS
// ---------------------------------------------------------------------------
__global__ __launch_bounds__(256) void transpose_kernel(
    const float* __restrict__ W, unsigned short* __restrict__ WT, int K, int N)
{
    __shared__ unsigned short T[64][80];
    const int tid = threadIdx.x;
    const int n0 = blockIdx.x * 64, k0 = blockIdx.y * 64;

    int r  = tid >> 2;
    int cq = tid & 3;
    const float* src = W + (size_t)(k0 + r) * N + n0 + cq*16;
    #pragma unroll
    for (int q = 0; q < 4; ++q) {
        f32x4 v = *reinterpret_cast<const f32x4*>(src + q*4);
        #pragma unroll
        for (int j = 0; j < 4; ++j) T[cq*16 + q*4 + j][r] = f2bf(v[j]);
    }
    __syncthreads();
    int c  = tid >> 2;
    int rq = tid & 3;
    short8 o0 = *reinterpret_cast<const short8*>(&T[c][rq*16]);
    short8 o1 = *reinterpret_cast<const short8*>(&T[c][rq*16 + 8]);
    unsigned short* dst = WT + (size_t)(n0 + c) * K + k0 + rq*16;
    *reinterpret_cast<short8*>(dst)     = o0;
    *reinterpret_cast<short8*>(dst + 8) = o1;
}

// ---------------------------------------------------------------------------
// Y = A[M,K](bf16) @ BT[N,K]^T(bf16) + bias(f32).  128x128 tile, BK=64,
// 4 waves (2x2), global_load_lds w/ pre-swizzled source, swizzled ds_read.
// XCD-aware bijective block swizzle (requires nwg % 8 == 0).
// FUSE: also write vtg[b][h][d][s] (bf16 V^T) and f32 present k/v slices.
// ---------------------------------------------------------------------------
template<int Y_F32, int FUSE>
__global__ __launch_bounds__(256) void gemm_bt_kernel(
    const unsigned short* __restrict__ A, const unsigned short* __restrict__ BT,
    const float* __restrict__ bias, void* __restrict__ Yv,
    unsigned short* __restrict__ vtg, float* __restrict__ pres,
    int M, int N, int K)
{
    __shared__ unsigned short sA[128*64];
    __shared__ unsigned short sB[128*64];

    const int tid = threadIdx.x, lane = tid & 63, w = tid >> 6;
    const int l15 = lane & 15, lg = lane >> 4;

    // XCD-aware swizzle: bid -> (bid%8)*(nwg/8) + bid/8
    const int nwg = gridDim.x * gridDim.y;
    const int bid = blockIdx.y * gridDim.x + blockIdx.x;
    const int swz = (bid & 7) * (nwg >> 3) + (bid >> 3);
    const int n0 = (swz % gridDim.x) * 128;
    const int m0 = (swz / gridDim.x) * 128;

    const int wr = w >> 1, wc = w & 1;

    f32x4 acc[4][4];
    #pragma unroll
    for (int m = 0; m < 4; ++m)
        #pragma unroll
        for (int n = 0; n < 4; ++n) acc[m][n] = f32x4{0,0,0,0};

    const int ldrow = (lane >> 3);
    const int slot  = lane & 7;

    for (int k0 = 0; k0 < K; k0 += 64) {
        #pragma unroll
        for (int i = 0; i < 4; ++i) {
            int kb  = w*4 + i;
            int row = kb*8 + ldrow;
            int sc  = slot ^ (row & 7);
            gload_lds16(&A [(size_t)(m0 + row) * K + k0 + sc*8], &sA[kb*512]);
            gload_lds16(&BT[(size_t)(n0 + row) * K + k0 + sc*8], &sB[kb*512]);
        }
        __syncthreads();

        #pragma unroll
        for (int kk = 0; kk < 2; ++kk) {
            short8 af[4], bfr[4];
            #pragma unroll
            for (int m = 0; m < 4; ++m) {
                int row = wr*64 + m*16 + l15;
                int ch  = (4*kk + lg) ^ (row & 7);
                af[m] = *reinterpret_cast<const short8*>(&sA[row*64 + ch*8]);
            }
            #pragma unroll
            for (int n = 0; n < 4; ++n) {
                int row = wc*64 + n*16 + l15;
                int ch  = (4*kk + lg) ^ (row & 7);
                bfr[n] = *reinterpret_cast<const short8*>(&sB[row*64 + ch*8]);
            }
            __builtin_amdgcn_s_setprio(1);
            #pragma unroll
            for (int m = 0; m < 4; ++m)
                #pragma unroll
                for (int n = 0; n < 4; ++n)
                    acc[m][n] = __builtin_amdgcn_mfma_f32_16x16x32_bf16(
                        af[m], bfr[n], acc[m][n], 0, 0, 0);
            __builtin_amdgcn_s_setprio(0);
        }
        __syncthreads();
    }

    #pragma unroll
    for (int n = 0; n < 4; ++n) {
        int col = n0 + wc*64 + n*16 + l15;
        float bv = bias[col];
        #pragma unroll
        for (int m = 0; m < 4; ++m) {
            int row0 = m0 + wr*64 + m*16 + lg*4;
            float v0 = acc[m][n][0] + bv;
            float v1 = acc[m][n][1] + bv;
            float v2 = acc[m][n][2] + bv;
            float v3 = acc[m][n][3] + bv;
            if (Y_F32) {
                float* Y = (float*)Yv;
                Y[(size_t)(row0+0) * N + col] = v0;
                Y[(size_t)(row0+1) * N + col] = v1;
                Y[(size_t)(row0+2) * N + col] = v2;
                Y[(size_t)(row0+3) * N + col] = v3;
            } else {
                unsigned short* Y = (unsigned short*)Yv;
                Y[(size_t)(row0+0) * N + col] = f2bf(v0);
                Y[(size_t)(row0+1) * N + col] = f2bf(v1);
                Y[(size_t)(row0+2) * N + col] = f2bf(v2);
                Y[(size_t)(row0+3) * N + col] = f2bf(v3);
            }
            if (FUSE && n0 < D_MODEL) {   // V cols: vtg (bf16 V^T) + f32 present[1]
                int hh = col >> 6, dd = col & 63;
                int bb = row0 >> 11, ss = row0 & (SEQ - 1);
                short4v pk;
                pk[0] = (short)f2bf(v0); pk[1] = (short)f2bf(v1);
                pk[2] = (short)f2bf(v2); pk[3] = (short)f2bf(v3);
                *reinterpret_cast<short4v*>(
                    vtg + (((size_t)bb*HEADS + hh)*KD + dd)*SEQ + ss) = pk;
                float* pv = pres + (size_t)BATCH*HEADS*SEQ*KD
                          + (((size_t)bb*HEADS + hh)*SEQ + ss)*KD + dd;
                pv[0] = v0; pv[KD] = v1; pv[2*KD] = v2; pv[3*KD] = v3;
            }
            if (FUSE && n0 >= 2*D_MODEL) {  // K cols: f32 present[0]
                int rel = col - 2*D_MODEL;
                int hh = rel >> 6, dd = rel & 63;
                int bb = row0 >> 11, ss = row0 & (SEQ - 1);
                float* pk2 = pres + (((size_t)bb*HEADS + hh)*SEQ + ss)*KD + dd;
                pk2[0] = v0; pk2[KD] = v1; pk2[2*KD] = v2; pk2[3*KD] = v3;
            }
        }
    }
}

// ---------------------------------------------------------------------------
// Flash attention, swapped-operand 32x32 MFMA, merged 64-key stage,
// work-balanced q-pairing, XCD-grouped grid (8 q-blocks of one (b,h)
// share bid%8 -> same XCD L2 for K/V).
// ---------------------------------------------------------------------------
__global__ __launch_bounds__(256) void attn_kernel(
    const unsigned short* __restrict__ qkv,
    const unsigned short* __restrict__ vtg,
    unsigned short* __restrict__ aout)
{
    __shared__ unsigned short Kl[2][64*64];   // [key][d-chunk swz]
    __shared__ unsigned short Vl[2][64*64];   // [d][key-chunk swz]

    const int tid  = threadIdx.x;
    const int lane = tid & 63;
    const int w    = tid >> 6;
    const int l31  = lane & 31, hi = lane >> 5;

    const int bid   = blockIdx.x;       // 0..511
    const int hb    = bid & 63;         // (b,h): xcd = hb & 7
    const int qpair = bid >> 6;         // 0..7
    const int h = hb & 15, b = hb >> 4;

    const unsigned short* base  = qkv + (size_t)b * SEQ * QKV_N;
    const unsigned short* vbase = vtg + ((size_t)b * HEADS + h) * KD * SEQ;
    const int qoff = D_MODEL + h*KD;
    const int koff = 2*D_MODEL + h*KD;

    const float SCALE2 = 0.125f * 1.44269504088896f;   // 0.18034
    const float THR_RAW = 44.36f;                      // 8 / SCALE2

    const int ldrow = lane >> 3;
    const int slot  = lane & 7;
    const int ksw   = l31 & 7;

    for (int pass = 0; pass < 2; ++pass) {
        const int qb = pass ? (15 - qpair) : qpair;
        const int q0 = qb * 128;
        const int qrow  = q0 + w*32 + l31;
        const int qminw = q0 + w*32;

        short8 qf[4];
        #pragma unroll
        for (int ks = 0; ks < 4; ++ks)
            qf[ks] = *reinterpret_cast<const short8*>(
                base + (size_t)qrow * QKV_N + qoff + ks*16 + hi*8);

        f32x16 o0, o1;
        #pragma unroll
        for (int r = 0; r < 16; ++r) { o0[r] = 0.f; o1[r] = 0.f; }
        float m = -1e30f, msc = -1e30f * 0.180336887f, sr = 0.f;

        const int nt = 2*qb + 2;

        // prologue: stage tile 0
        #pragma unroll
        for (int i = 0; i < 2; ++i) {
            int kb = w*2 + i, row = kb*8 + ldrow, sc = slot ^ (row & 7);
            gload_lds16(&base[(size_t)row * QKV_N + koff + sc*8], &Kl[0][kb*512]);
            gload_lds16(&vbase[(size_t)row * SEQ + sc*8],         &Vl[0][kb*512]);
        }
        __syncthreads();

        for (int t = 0; t < nt; ++t) {
            const int buf = t & 1;

            if (t + 1 < nt) {   // prefetch next tile (async over compute)
                #pragma unroll
                for (int i = 0; i < 2; ++i) {
                    int kb = w*2 + i, row = kb*8 + ldrow, sc = slot ^ (row & 7);
                    gload_lds16(&base[(size_t)((t+1)*64 + row) * QKV_N + koff + sc*8],
                                &Kl[buf^1][kb*512]);
                    gload_lds16(&vbase[(size_t)row * SEQ + (t+1)*64 + sc*8],
                                &Vl[buf^1][kb*512]);
                }
            }

            const int d0 = qminw - t*64;
            if (d0 > -32) {    // wave has work in this 64-key tile
                // ---- QK^T both 32-key halves ----
                f32x16 sa, sb;
                #pragma unroll
                for (int r = 0; r < 16; ++r) { sa[r] = 0.f; sb[r] = 0.f; }
                __builtin_amdgcn_s_setprio(1);
                #pragma unroll
                for (int ks = 0; ks < 4; ++ks) {
                    short8 kf = *reinterpret_cast<const short8*>(
                        &Kl[buf][l31*64 + ((2*ks + hi) ^ ksw)*8]);
                    sa = __builtin_amdgcn_mfma_f32_32x32x16_bf16(kf, qf[ks], sa, 0, 0, 0);
                }
                #pragma unroll
                for (int ks = 0; ks < 4; ++ks) {
                    short8 kf = *reinterpret_cast<const short8*>(
                        &Kl[buf][(32 + l31)*64 + ((2*ks + hi) ^ ksw)*8]);
                    sb = __builtin_amdgcn_mfma_f32_32x32x16_bf16(kf, qf[ks], sb, 0, 0, 0);
                }
                __builtin_amdgcn_s_setprio(0);

                // ---- causal mask (keys: A half = t*64+cr+4hi, B half = +32) ----
                if (d0 <= 32) {
                    const int kqA = l31 + d0      - 4*hi;
                    const int kqB = l31 + d0 - 32 - 4*hi;
                    #pragma unroll
                    for (int r = 0; r < 16; ++r) {
                        const int cr = (r & 3) + 8*(r >> 2);
                        if (d0 == 0) sa[r] = (cr <= kqA) ? sa[r] : -1e30f;
                        sb[r] = (cr <= kqB) ? sb[r] : -1e30f;
                    }
                }

                // ---- max tree over 32 + cross-pair, defer-rescale ----
                float x[8];
                #pragma unroll
                for (int i = 0; i < 8; ++i)
                    x[i] = fmaxf(fmaxf(sa[2*i], sa[2*i+1]), fmaxf(sb[2*i], sb[2*i+1]));
                float pm = fmaxf(fmaxf(fmaxf(x[0], x[1]), fmaxf(x[2], x[3])),
                                 fmaxf(fmaxf(x[4], x[5]), fmaxf(x[6], x[7])));
                pm = pairmax(pm);
                if (!__all(pm <= m + THR_RAW)) {
                    float mn  = fmaxf(m, pm);
                    float fac = exp2f((m - mn) * SCALE2);
                    sr *= fac;
                    #pragma unroll
                    for (int r = 0; r < 16; ++r) { o0[r] *= fac; o1[r] *= fac; }
                    m = mn; msc = m * SCALE2;
                }

                // ---- exp + tree sum ----
                #pragma unroll
                for (int r = 0; r < 16; ++r) {
                    sa[r] = exp2f(sa[r]*SCALE2 - msc);
                    sb[r] = exp2f(sb[r]*SCALE2 - msc);
                }
                float u[8];
                #pragma unroll
                for (int i = 0; i < 8; ++i)
                    u[i] = (sa[2*i] + sa[2*i+1]) + (sb[2*i] + sb[2*i+1]);
                float ts = ((u[0]+u[1]) + (u[2]+u[3])) + ((u[4]+u[5]) + (u[6]+u[7]));
                sr += pairsum(ts);

                // ---- pack P to bf16 ----
                u32 WA[8], WB[8];
                #pragma unroll
                for (int wi = 0; wi < 8; ++wi) {
                    WA[wi] = cvtpk(sa[2*wi], sa[2*wi+1]);
                    WB[wi] = cvtpk(sb[2*wi], sb[2*wi+1]);
                }

                // ---- PV: O^T += V^T @ P^T (proven shfl-based cross-half pack) ----
                #pragma unroll
                for (int h32 = 0; h32 < 2; ++h32) {
                    #pragma unroll
                    for (int ks = 0; ks < 2; ++ks) {
                        u32 W0 = h32 ? WB[4*ks+0] : WA[4*ks+0];
                        u32 W1 = h32 ? WB[4*ks+1] : WA[4*ks+1];
                        u32 W2 = h32 ? WB[4*ks+2] : WA[4*ks+2];
                        u32 W3 = h32 ? WB[4*ks+3] : WA[4*ks+3];
                        u32 s0 = hi ? W0 : W2;
                        u32 s1 = hi ? W1 : W3;
                        u32 r0 = (u32)__shfl_xor((int)s0, 32, 64);
                        u32 r1 = (u32)__shfl_xor((int)s1, 32, 64);
                        u32x4 wv;
                        wv[0] = hi ? r0 : W0;
                        wv[1] = hi ? r1 : W1;
                        wv[2] = hi ? W2 : r0;
                        wv[3] = hi ? W3 : r1;
                        short8 pfrag = __builtin_bit_cast(short8, wv);
                        __builtin_amdgcn_s_setprio(1);
                        #pragma unroll
                        for (int dt = 0; dt < 2; ++dt) {
                            short8 vf = *reinterpret_cast<const short8*>(
                                &Vl[buf][(dt*32 + l31)*64 + ((4*h32 + 2*ks + hi) ^ ksw)*8]);
                            if (dt == 0)
                                o0 = __builtin_amdgcn_mfma_f32_32x32x16_bf16(vf, pfrag, o0, 0, 0, 0);
                            else
                                o1 = __builtin_amdgcn_mfma_f32_32x32x16_bf16(vf, pfrag, o1, 0, 0, 0);
                        }
                        __builtin_amdgcn_s_setprio(0);
                    }
                }
            }
            __syncthreads();
        }

        // ---- epilogue ----
        const float inv = 1.0f / sr;
        unsigned short* orow = aout + ((size_t)b * SEQ + qrow) * D_MODEL + h*KD;
        #pragma unroll
        for (int dt = 0; dt < 2; ++dt) {
            #pragma unroll
            for (int g = 0; g < 4; ++g) {
                short4v pk;
                #pragma unroll
                for (int j = 0; j < 4; ++j) {
                    float v = (dt == 0 ? o0[4*g + j] : o1[4*g + j]) * inv;
                    pk[j] = (short)f2bf(v);
                }
                *reinterpret_cast<short4v*>(orow + dt*32 + 8*g + 4*hi) = pk;
            }
        }
    }
}

// ---------------------------------------------------------------------------
extern "C" void kernel_launch(void* const* d_in, const int* in_sizes, int n_in,
                              void* d_out, int out_size, void* d_ws, size_t ws_size,
                              hipStream_t stream)
{
    const float* x      = (const float*)d_in[0];
    const float* W_attn = (const float*)d_in[1];
    const float* b_attn = (const float*)d_in[2];
    const float* W_proj = (const float*)d_in[3];
    const float* b_proj = (const float*)d_in[4];
    float* out = (float*)d_out;

    unsigned short* qkv  = (unsigned short*)d_ws;                  // [8192][3072]
    unsigned short* xbf  = qkv + (size_t)NTOK * QKV_N;             // [8192][1024] (= aout later)
    unsigned short* aout = xbf;
    unsigned short* WT   = xbf + (size_t)NTOK * D_MODEL;           // [3072][1024]
    unsigned short* WpT  = WT + (size_t)QKV_N * D_MODEL;           // [1024][1024]
    unsigned short* vtg  = WpT + (size_t)D_MODEL * D_MODEL;        // [4][16][64][2048]
    float* pres = out + (size_t)NTOK * D_MODEL;                    // [2,4,16,2048,64] f32

    cvt_kernel<<<(NTOK * D_MODEL / 8) / 256, 256, 0, stream>>>(x, xbf);
    dim3 gt1(QKV_N / 64, D_MODEL / 64);
    transpose_kernel<<<gt1, 256, 0, stream>>>(W_attn, WT, D_MODEL, QKV_N);
    dim3 gt2(D_MODEL / 64, D_MODEL / 64);
    transpose_kernel<<<gt2, 256, 0, stream>>>(W_proj, WpT, D_MODEL, D_MODEL);

    // qkv = x @ W_attn + b_attn  (+ fused V^T copy and f32 present k/v)
    dim3 g1(QKV_N / 128, NTOK / 128);
    gemm_bt_kernel<0, 1><<<g1, 256, 0, stream>>>(xbf, WT, b_attn, qkv, vtg, pres,
                                                 NTOK, QKV_N, D_MODEL);

    // causal attention (swapped-operand, merged 64-key stage, XCD-grouped)
    attn_kernel<<<512, 256, 0, stream>>>(qkv, vtg, aout);

    // out = aout @ W_proj + b_proj
    dim3 g2(D_MODEL / 128, NTOK / 128);
    gemm_bt_kernel<1, 0><<<g2, 256, 0, stream>>>(aout, WpT, b_proj, out,
                                                 nullptr, nullptr,
                                                 NTOK, D_MODEL, D_MODEL);
}

// Round 9
// 215.093 us; speedup vs baseline: 3.2516x; 1.0073x over previous
//
#include <hip/hip_runtime.h>

typedef __attribute__((ext_vector_type(8))) short short8;
typedef __attribute__((ext_vector_type(4))) short short4v;
typedef __attribute__((ext_vector_type(4))) float f32x4;
typedef __attribute__((ext_vector_type(16))) float f32x16;
typedef __attribute__((ext_vector_type(4))) unsigned int u32x4;
typedef __attribute__((ext_vector_type(2))) unsigned int u32x2;
typedef unsigned int u32;

#define D_MODEL 1024
#define HEADS 16
#define KD 64
#define SEQ 2048
#define BATCH 4
#define NTOK (BATCH*SEQ)    /* 8192 */
#define QKV_N (3*D_MODEL)   /* 3072 */

__device__ inline float bf2f(unsigned short u) {
    unsigned x = ((unsigned)u) << 16;
    return __builtin_bit_cast(float, x);
}
__device__ inline unsigned short f2bf(float f) {
    unsigned u = __builtin_bit_cast(unsigned, f);
    u += 0x7FFFu + ((u >> 16) & 1u);
    return (unsigned short)(u >> 16);
}
__device__ __forceinline__ void gload_lds16(const unsigned short* g, unsigned short* l) {
    __builtin_amdgcn_global_load_lds(
        (const __attribute__((address_space(1))) void*)g,
        (__attribute__((address_space(3))) void*)l, 16, 0, 0);
}
__device__ __forceinline__ u32 cvtpk(float lo, float hi) {
    u32 r; asm("v_cvt_pk_bf16_f32 %0, %1, %2" : "=v"(r) : "v"(lo), "v"(hi)); return r;
}
// Half-exchange across the lane<32 / lane>=32 split.
__device__ __forceinline__ void pl32swap(u32& a, u32& b) {
#if __has_builtin(__builtin_amdgcn_permlane32_swap)
    u32x2 r = __builtin_amdgcn_permlane32_swap(a, b, 0, 0);
    a = r[0]; b = r[1];
#else
    u32 pa = (u32)__shfl_xor((int)a, 32, 64);
    u32 pb = (u32)__shfl_xor((int)b, 32, 64);
    bool hb = (threadIdx.x & 32) != 0;
    u32 na = hb ? pb : a;
    u32 nb = hb ? b : pa;
    a = na; b = nb;
#endif
}
// Order-robust reductions: correct for any half-exchange return convention.
__device__ __forceinline__ float pairmax(float x) {
    u32 a = __builtin_bit_cast(u32, x), b = a;
    pl32swap(a, b);
    return fmaxf(x, fmaxf(__builtin_bit_cast(float, a), __builtin_bit_cast(float, b)));
}
__device__ __forceinline__ float pairsum(float x) {
    u32 a = __builtin_bit_cast(u32, x), b = a;
    pl32swap(a, b);
    return __builtin_bit_cast(float, a) + __builtin_bit_cast(float, b);
}

// ---------------------------------------------------------------------------
// x (f32) -> bf16, elementwise, 8 per thread
// ---------------------------------------------------------------------------
__global__ __launch_bounds__(256) void cvt_kernel(
    const float* __restrict__ x, unsigned short* __restrict__ y)
{
    size_t i = (size_t)blockIdx.x * 256 + threadIdx.x;
    f32x4 a = *reinterpret_cast<const f32x4*>(x + i*8);
    f32x4 b = *reinterpret_cast<const f32x4*>(x + i*8 + 4);
    short8 o;
    #pragma unroll
    for (int j = 0; j < 4; ++j) { o[j] = (short)f2bf(a[j]); o[j+4] = (short)f2bf(b[j]); }
    *reinterpret_cast<short8*>(y + i*8) = o;
}

// ---------------------------------------------------------------------------
// WT[n][k] = bf16(W[k][n]); tile 64x64 via LDS
// ---------------------------------------------------------------------------
__global__ __launch_bounds__(256) void transpose_kernel(
    const float* __restrict__ W, unsigned short* __restrict__ WT, int K, int N)
{
    __shared__ unsigned short T[64][80];
    const int tid = threadIdx.x;
    const int n0 = blockIdx.x * 64, k0 = blockIdx.y * 64;

    int r  = tid >> 2;
    int cq = tid & 3;
    const float* src = W + (size_t)(k0 + r) * N + n0 + cq*16;
    #pragma unroll
    for (int q = 0; q < 4; ++q) {
        f32x4 v = *reinterpret_cast<const f32x4*>(src + q*4);
        #pragma unroll
        for (int j = 0; j < 4; ++j) T[cq*16 + q*4 + j][r] = f2bf(v[j]);
    }
    __syncthreads();
    int c  = tid >> 2;
    int rq = tid & 3;
    short8 o0 = *reinterpret_cast<const short8*>(&T[c][rq*16]);
    short8 o1 = *reinterpret_cast<const short8*>(&T[c][rq*16 + 8]);
    unsigned short* dst = WT + (size_t)(n0 + c) * K + k0 + rq*16;
    *reinterpret_cast<short8*>(dst)     = o0;
    *reinterpret_cast<short8*>(dst + 8) = o1;
}

// ---------------------------------------------------------------------------
// Y = A[M,K](bf16) @ BT[N,K]^T(bf16) + bias(f32).  128x128 tile, BK=64,
// 4 waves (2x2), global_load_lds w/ pre-swizzled source, swizzled ds_read.
// XCD-aware bijective block swizzle (requires nwg % 8 == 0).
// FUSE: also write vtg[b][h][d][s] (bf16 V^T) and f32 present k/v slices.
// ---------------------------------------------------------------------------
template<int Y_F32, int FUSE>
__global__ __launch_bounds__(256) void gemm_bt_kernel(
    const unsigned short* __restrict__ A, const unsigned short* __restrict__ BT,
    const float* __restrict__ bias, void* __restrict__ Yv,
    unsigned short* __restrict__ vtg, float* __restrict__ pres,
    int M, int N, int K)
{
    __shared__ unsigned short sA[128*64];
    __shared__ unsigned short sB[128*64];

    const int tid = threadIdx.x, lane = tid & 63, w = tid >> 6;
    const int l15 = lane & 15, lg = lane >> 4;

    // XCD-aware swizzle: bid -> (bid%8)*(nwg/8) + bid/8
    const int nwg = gridDim.x * gridDim.y;
    const int bid = blockIdx.y * gridDim.x + blockIdx.x;
    const int swz = (bid & 7) * (nwg >> 3) + (bid >> 3);
    const int n0 = (swz % gridDim.x) * 128;
    const int m0 = (swz / gridDim.x) * 128;

    const int wr = w >> 1, wc = w & 1;

    f32x4 acc[4][4];
    #pragma unroll
    for (int m = 0; m < 4; ++m)
        #pragma unroll
        for (int n = 0; n < 4; ++n) acc[m][n] = f32x4{0,0,0,0};

    const int ldrow = (lane >> 3);
    const int slot  = lane & 7;

    for (int k0 = 0; k0 < K; k0 += 64) {
        #pragma unroll
        for (int i = 0; i < 4; ++i) {
            int kb  = w*4 + i;
            int row = kb*8 + ldrow;
            int sc  = slot ^ (row & 7);
            gload_lds16(&A [(size_t)(m0 + row) * K + k0 + sc*8], &sA[kb*512]);
            gload_lds16(&BT[(size_t)(n0 + row) * K + k0 + sc*8], &sB[kb*512]);
        }
        __syncthreads();

        #pragma unroll
        for (int kk = 0; kk < 2; ++kk) {
            short8 af[4], bfr[4];
            #pragma unroll
            for (int m = 0; m < 4; ++m) {
                int row = wr*64 + m*16 + l15;
                int ch  = (4*kk + lg) ^ (row & 7);
                af[m] = *reinterpret_cast<const short8*>(&sA[row*64 + ch*8]);
            }
            #pragma unroll
            for (int n = 0; n < 4; ++n) {
                int row = wc*64 + n*16 + l15;
                int ch  = (4*kk + lg) ^ (row & 7);
                bfr[n] = *reinterpret_cast<const short8*>(&sB[row*64 + ch*8]);
            }
            __builtin_amdgcn_s_setprio(1);
            #pragma unroll
            for (int m = 0; m < 4; ++m)
                #pragma unroll
                for (int n = 0; n < 4; ++n)
                    acc[m][n] = __builtin_amdgcn_mfma_f32_16x16x32_bf16(
                        af[m], bfr[n], acc[m][n], 0, 0, 0);
            __builtin_amdgcn_s_setprio(0);
        }
        __syncthreads();
    }

    #pragma unroll
    for (int n = 0; n < 4; ++n) {
        int col = n0 + wc*64 + n*16 + l15;
        float bv = bias[col];
        #pragma unroll
        for (int m = 0; m < 4; ++m) {
            int row0 = m0 + wr*64 + m*16 + lg*4;
            float v0 = acc[m][n][0] + bv;
            float v1 = acc[m][n][1] + bv;
            float v2 = acc[m][n][2] + bv;
            float v3 = acc[m][n][3] + bv;
            if (Y_F32) {
                float* Y = (float*)Yv;
                Y[(size_t)(row0+0) * N + col] = v0;
                Y[(size_t)(row0+1) * N + col] = v1;
                Y[(size_t)(row0+2) * N + col] = v2;
                Y[(size_t)(row0+3) * N + col] = v3;
            } else {
                unsigned short* Y = (unsigned short*)Yv;
                Y[(size_t)(row0+0) * N + col] = f2bf(v0);
                Y[(size_t)(row0+1) * N + col] = f2bf(v1);
                Y[(size_t)(row0+2) * N + col] = f2bf(v2);
                Y[(size_t)(row0+3) * N + col] = f2bf(v3);
            }
            if (FUSE && n0 < D_MODEL) {   // V cols: vtg (bf16 V^T) + f32 present[1]
                int hh = col >> 6, dd = col & 63;
                int bb = row0 >> 11, ss = row0 & (SEQ - 1);
                short4v pk;
                pk[0] = (short)f2bf(v0); pk[1] = (short)f2bf(v1);
                pk[2] = (short)f2bf(v2); pk[3] = (short)f2bf(v3);
                *reinterpret_cast<short4v*>(
                    vtg + (((size_t)bb*HEADS + hh)*KD + dd)*SEQ + ss) = pk;
                float* pv = pres + (size_t)BATCH*HEADS*SEQ*KD
                          + (((size_t)bb*HEADS + hh)*SEQ + ss)*KD + dd;
                pv[0] = v0; pv[KD] = v1; pv[2*KD] = v2; pv[3*KD] = v3;
            }
            if (FUSE && n0 >= 2*D_MODEL) {  // K cols: f32 present[0]
                int rel = col - 2*D_MODEL;
                int hh = rel >> 6, dd = rel & 63;
                int bb = row0 >> 11, ss = row0 & (SEQ - 1);
                float* pk2 = pres + (((size_t)bb*HEADS + hh)*SEQ + ss)*KD + dd;
                pk2[0] = v0; pk2[KD] = v1; pk2[2*KD] = v2; pk2[3*KD] = v3;
            }
        }
    }
}

// ---------------------------------------------------------------------------
// Flash attention, swapped-operand 32x32 MFMA, merged 64-key stage.
// One 128-row q-tile per block -> 1024 blocks (4/CU resident); largest
// q-tiles dispatched first for load balance; XCD-grouped (bid&63 = (b,h)).
// ---------------------------------------------------------------------------
__global__ __launch_bounds__(256) void attn_kernel(
    const unsigned short* __restrict__ qkv,
    const unsigned short* __restrict__ vtg,
    unsigned short* __restrict__ aout)
{
    __shared__ unsigned short Kl[2][64*64];   // [key][d-chunk swz]
    __shared__ unsigned short Vl[2][64*64];   // [d][key-chunk swz]

    const int tid  = threadIdx.x;
    const int lane = tid & 63;
    const int w    = tid >> 6;
    const int l31  = lane & 31, hi = lane >> 5;

    const int bid = blockIdx.x;        // 0..1023
    const int hb  = bid & 63;          // (b,h): xcd = hb & 7, stable per (b,h)
    const int qb  = 15 - (bid >> 6);   // 15..0 : biggest tiles first
    const int h = hb & 15, b = hb >> 4;

    const unsigned short* base  = qkv + (size_t)b * SEQ * QKV_N;
    const unsigned short* vbase = vtg + ((size_t)b * HEADS + h) * KD * SEQ;
    const int qoff = D_MODEL + h*KD;
    const int koff = 2*D_MODEL + h*KD;

    const float SCALE2 = 0.125f * 1.44269504088896f;   // 0.18034
    const float THR_RAW = 44.36f;                      // 8 / SCALE2

    const int ldrow = lane >> 3;
    const int slot  = lane & 7;
    const int ksw   = l31 & 7;

    const int q0 = qb * 128;
    const int qrow  = q0 + w*32 + l31;
    const int qminw = q0 + w*32;

    short8 qf[4];
    #pragma unroll
    for (int ks = 0; ks < 4; ++ks)
        qf[ks] = *reinterpret_cast<const short8*>(
            base + (size_t)qrow * QKV_N + qoff + ks*16 + hi*8);

    f32x16 o0, o1;
    #pragma unroll
    for (int r = 0; r < 16; ++r) { o0[r] = 0.f; o1[r] = 0.f; }
    float m = -1e30f, msc = -1e30f * 0.180336887f, sr = 0.f;

    const int nt = 2*qb + 2;

    // prologue: stage tile 0
    #pragma unroll
    for (int i = 0; i < 2; ++i) {
        int kb = w*2 + i, row = kb*8 + ldrow, sc = slot ^ (row & 7);
        gload_lds16(&base[(size_t)row * QKV_N + koff + sc*8], &Kl[0][kb*512]);
        gload_lds16(&vbase[(size_t)row * SEQ + sc*8],         &Vl[0][kb*512]);
    }
    __syncthreads();

    for (int t = 0; t < nt; ++t) {
        const int buf = t & 1;

        if (t + 1 < nt) {   // prefetch next tile (async over compute)
            #pragma unroll
            for (int i = 0; i < 2; ++i) {
                int kb = w*2 + i, row = kb*8 + ldrow, sc = slot ^ (row & 7);
                gload_lds16(&base[(size_t)((t+1)*64 + row) * QKV_N + koff + sc*8],
                            &Kl[buf^1][kb*512]);
                gload_lds16(&vbase[(size_t)row * SEQ + (t+1)*64 + sc*8],
                            &Vl[buf^1][kb*512]);
            }
        }

        const int d0 = qminw - t*64;
        if (d0 > -32) {    // wave has work in this 64-key tile
            // ---- QK^T both 32-key halves ----
            f32x16 sa, sb;
            #pragma unroll
            for (int r = 0; r < 16; ++r) { sa[r] = 0.f; sb[r] = 0.f; }
            __builtin_amdgcn_s_setprio(1);
            #pragma unroll
            for (int ks = 0; ks < 4; ++ks) {
                short8 kf = *reinterpret_cast<const short8*>(
                    &Kl[buf][l31*64 + ((2*ks + hi) ^ ksw)*8]);
                sa = __builtin_amdgcn_mfma_f32_32x32x16_bf16(kf, qf[ks], sa, 0, 0, 0);
            }
            #pragma unroll
            for (int ks = 0; ks < 4; ++ks) {
                short8 kf = *reinterpret_cast<const short8*>(
                    &Kl[buf][(32 + l31)*64 + ((2*ks + hi) ^ ksw)*8]);
                sb = __builtin_amdgcn_mfma_f32_32x32x16_bf16(kf, qf[ks], sb, 0, 0, 0);
            }
            __builtin_amdgcn_s_setprio(0);

            // ---- causal mask (keys: A half = t*64+cr+4hi, B half = +32) ----
            if (d0 <= 32) {
                const int kqA = l31 + d0      - 4*hi;
                const int kqB = l31 + d0 - 32 - 4*hi;
                #pragma unroll
                for (int r = 0; r < 16; ++r) {
                    const int cr = (r & 3) + 8*(r >> 2);
                    if (d0 == 0) sa[r] = (cr <= kqA) ? sa[r] : -1e30f;
                    sb[r] = (cr <= kqB) ? sb[r] : -1e30f;
                }
            }

            // ---- max tree over 32 + cross-pair, defer-rescale ----
            float x[8];
            #pragma unroll
            for (int i = 0; i < 8; ++i)
                x[i] = fmaxf(fmaxf(sa[2*i], sa[2*i+1]), fmaxf(sb[2*i], sb[2*i+1]));
            float pm = fmaxf(fmaxf(fmaxf(x[0], x[1]), fmaxf(x[2], x[3])),
                             fmaxf(fmaxf(x[4], x[5]), fmaxf(x[6], x[7])));
            pm = pairmax(pm);
            if (!__all(pm <= m + THR_RAW)) {
                float mn  = fmaxf(m, pm);
                float fac = exp2f((m - mn) * SCALE2);
                sr *= fac;
                #pragma unroll
                for (int r = 0; r < 16; ++r) { o0[r] *= fac; o1[r] *= fac; }
                m = mn; msc = m * SCALE2;
            }

            // ---- exp + tree sum ----
            #pragma unroll
            for (int r = 0; r < 16; ++r) {
                sa[r] = exp2f(sa[r]*SCALE2 - msc);
                sb[r] = exp2f(sb[r]*SCALE2 - msc);
            }
            float u[8];
            #pragma unroll
            for (int i = 0; i < 8; ++i)
                u[i] = (sa[2*i] + sa[2*i+1]) + (sb[2*i] + sb[2*i+1]);
            float ts = ((u[0]+u[1]) + (u[2]+u[3])) + ((u[4]+u[5]) + (u[6]+u[7]));
            sr += pairsum(ts);

            // ---- pack P to bf16 ----
            u32 WA[8], WB[8];
            #pragma unroll
            for (int wi = 0; wi < 8; ++wi) {
                WA[wi] = cvtpk(sa[2*wi], sa[2*wi+1]);
                WB[wi] = cvtpk(sb[2*wi], sb[2*wi+1]);
            }

            // ---- PV: O^T += V^T @ P^T (proven shfl-based cross-half pack) ----
            #pragma unroll
            for (int h32 = 0; h32 < 2; ++h32) {
                #pragma unroll
                for (int ks = 0; ks < 2; ++ks) {
                    u32 W0 = h32 ? WB[4*ks+0] : WA[4*ks+0];
                    u32 W1 = h32 ? WB[4*ks+1] : WA[4*ks+1];
                    u32 W2 = h32 ? WB[4*ks+2] : WA[4*ks+2];
                    u32 W3 = h32 ? WB[4*ks+3] : WA[4*ks+3];
                    u32 s0 = hi ? W0 : W2;
                    u32 s1 = hi ? W1 : W3;
                    u32 r0 = (u32)__shfl_xor((int)s0, 32, 64);
                    u32 r1 = (u32)__shfl_xor((int)s1, 32, 64);
                    u32x4 wv;
                    wv[0] = hi ? r0 : W0;
                    wv[1] = hi ? r1 : W1;
                    wv[2] = hi ? W2 : r0;
                    wv[3] = hi ? W3 : r1;
                    short8 pfrag = __builtin_bit_cast(short8, wv);
                    __builtin_amdgcn_s_setprio(1);
                    #pragma unroll
                    for (int dt = 0; dt < 2; ++dt) {
                        short8 vf = *reinterpret_cast<const short8*>(
                            &Vl[buf][(dt*32 + l31)*64 + ((4*h32 + 2*ks + hi) ^ ksw)*8]);
                        if (dt == 0)
                            o0 = __builtin_amdgcn_mfma_f32_32x32x16_bf16(vf, pfrag, o0, 0, 0, 0);
                        else
                            o1 = __builtin_amdgcn_mfma_f32_32x32x16_bf16(vf, pfrag, o1, 0, 0, 0);
                    }
                    __builtin_amdgcn_s_setprio(0);
                }
            }
        }
        __syncthreads();
    }

    // ---- epilogue ----
    const float inv = 1.0f / sr;
    unsigned short* orow = aout + ((size_t)b * SEQ + qrow) * D_MODEL + h*KD;
    #pragma unroll
    for (int dt = 0; dt < 2; ++dt) {
        #pragma unroll
        for (int g = 0; g < 4; ++g) {
            short4v pk;
            #pragma unroll
            for (int j = 0; j < 4; ++j) {
                float v = (dt == 0 ? o0[4*g + j] : o1[4*g + j]) * inv;
                pk[j] = (short)f2bf(v);
            }
            *reinterpret_cast<short4v*>(orow + dt*32 + 8*g + 4*hi) = pk;
        }
    }
}

// ---------------------------------------------------------------------------
extern "C" void kernel_launch(void* const* d_in, const int* in_sizes, int n_in,
                              void* d_out, int out_size, void* d_ws, size_t ws_size,
                              hipStream_t stream)
{
    const float* x      = (const float*)d_in[0];
    const float* W_attn = (const float*)d_in[1];
    const float* b_attn = (const float*)d_in[2];
    const float* W_proj = (const float*)d_in[3];
    const float* b_proj = (const float*)d_in[4];
    float* out = (float*)d_out;

    unsigned short* qkv  = (unsigned short*)d_ws;                  // [8192][3072]
    unsigned short* xbf  = qkv + (size_t)NTOK * QKV_N;             // [8192][1024] (= aout later)
    unsigned short* aout = xbf;
    unsigned short* WT   = xbf + (size_t)NTOK * D_MODEL;           // [3072][1024]
    unsigned short* WpT  = WT + (size_t)QKV_N * D_MODEL;           // [1024][1024]
    unsigned short* vtg  = WpT + (size_t)D_MODEL * D_MODEL;        // [4][16][64][2048]
    float* pres = out + (size_t)NTOK * D_MODEL;                    // [2,4,16,2048,64] f32

    cvt_kernel<<<(NTOK * D_MODEL / 8) / 256, 256, 0, stream>>>(x, xbf);
    dim3 gt1(QKV_N / 64, D_MODEL / 64);
    transpose_kernel<<<gt1, 256, 0, stream>>>(W_attn, WT, D_MODEL, QKV_N);
    dim3 gt2(D_MODEL / 64, D_MODEL / 64);
    transpose_kernel<<<gt2, 256, 0, stream>>>(W_proj, WpT, D_MODEL, D_MODEL);

    // qkv = x @ W_attn + b_attn  (+ fused V^T copy and f32 present k/v)
    dim3 g1(QKV_N / 128, NTOK / 128);
    gemm_bt_kernel<0, 1><<<g1, 256, 0, stream>>>(xbf, WT, b_attn, qkv, vtg, pres,
                                                 NTOK, QKV_N, D_MODEL);

    // causal attention (1024 blocks, biggest-first, XCD-grouped)
    attn_kernel<<<1024, 256, 0, stream>>>(qkv, vtg, aout);

    // out = aout @ W_proj + b_proj
    dim3 g2(D_MODEL / 128, NTOK / 128);
    gemm_bt_kernel<1, 0><<<g2, 256, 0, stream>>>(aout, WpT, b_proj, out,
                                                 nullptr, nullptr,
                                                 NTOK, D_MODEL, D_MODEL);
}

// Round 10
// 210.546 us; speedup vs baseline: 3.3218x; 1.0216x over previous
//
#include <hip/hip_runtime.h>

typedef __attribute__((ext_vector_type(8))) short short8;
typedef __attribute__((ext_vector_type(4))) short short4v;
typedef __attribute__((ext_vector_type(4))) float f32x4;
typedef __attribute__((ext_vector_type(16))) float f32x16;
typedef __attribute__((ext_vector_type(4))) unsigned int u32x4;
typedef __attribute__((ext_vector_type(2))) unsigned int u32x2;
typedef unsigned int u32;

#define D_MODEL 1024
#define HEADS 16
#define KD 64
#define SEQ 2048
#define BATCH 4
#define NTOK (BATCH*SEQ)    /* 8192 */
#define QKV_N (3*D_MODEL)   /* 3072 */

__device__ inline float bf2f(unsigned short u) {
    unsigned x = ((unsigned)u) << 16;
    return __builtin_bit_cast(float, x);
}
__device__ inline unsigned short f2bf(float f) {
    unsigned u = __builtin_bit_cast(unsigned, f);
    u += 0x7FFFu + ((u >> 16) & 1u);
    return (unsigned short)(u >> 16);
}
__device__ __forceinline__ void gload_lds16(const unsigned short* g, unsigned short* l) {
    __builtin_amdgcn_global_load_lds(
        (const __attribute__((address_space(1))) void*)g,
        (__attribute__((address_space(3))) void*)l, 16, 0, 0);
}
__device__ __forceinline__ u32 cvtpk(float lo, float hi) {
    u32 r; asm("v_cvt_pk_bf16_f32 %0, %1, %2" : "=v"(r) : "v"(lo), "v"(hi)); return r;
}
// Half-exchange across the lane<32 / lane>=32 split.
__device__ __forceinline__ void pl32swap(u32& a, u32& b) {
#if __has_builtin(__builtin_amdgcn_permlane32_swap)
    u32x2 r = __builtin_amdgcn_permlane32_swap(a, b, 0, 0);
    a = r[0]; b = r[1];
#else
    u32 pa = (u32)__shfl_xor((int)a, 32, 64);
    u32 pb = (u32)__shfl_xor((int)b, 32, 64);
    bool hb = (threadIdx.x & 32) != 0;
    u32 na = hb ? pb : a;
    u32 nb = hb ? b : pa;
    a = na; b = nb;
#endif
}
// Order-robust reductions: correct for any half-exchange return convention.
__device__ __forceinline__ float pairmax(float x) {
    u32 a = __builtin_bit_cast(u32, x), b = a;
    pl32swap(a, b);
    return fmaxf(x, fmaxf(__builtin_bit_cast(float, a), __builtin_bit_cast(float, b)));
}
__device__ __forceinline__ float pairsum(float x) {
    u32 a = __builtin_bit_cast(u32, x), b = a;
    pl32swap(a, b);
    return __builtin_bit_cast(float, a) + __builtin_bit_cast(float, b);
}

// ---------------------------------------------------------------------------
// x (f32) -> bf16, elementwise, 8 per thread
// ---------------------------------------------------------------------------
__global__ __launch_bounds__(256) void cvt_kernel(
    const float* __restrict__ x, unsigned short* __restrict__ y)
{
    size_t i = (size_t)blockIdx.x * 256 + threadIdx.x;
    f32x4 a = *reinterpret_cast<const f32x4*>(x + i*8);
    f32x4 b = *reinterpret_cast<const f32x4*>(x + i*8 + 4);
    short8 o;
    #pragma unroll
    for (int j = 0; j < 4; ++j) { o[j] = (short)f2bf(a[j]); o[j+4] = (short)f2bf(b[j]); }
    *reinterpret_cast<short8*>(y + i*8) = o;
}

// ---------------------------------------------------------------------------
// WT[n][k] = bf16(W[k][n]); tile 64x64 via LDS
// ---------------------------------------------------------------------------
__global__ __launch_bounds__(256) void transpose_kernel(
    const float* __restrict__ W, unsigned short* __restrict__ WT, int K, int N)
{
    __shared__ unsigned short T[64][80];
    const int tid = threadIdx.x;
    const int n0 = blockIdx.x * 64, k0 = blockIdx.y * 64;

    int r  = tid >> 2;
    int cq = tid & 3;
    const float* src = W + (size_t)(k0 + r) * N + n0 + cq*16;
    #pragma unroll
    for (int q = 0; q < 4; ++q) {
        f32x4 v = *reinterpret_cast<const f32x4*>(src + q*4);
        #pragma unroll
        for (int j = 0; j < 4; ++j) T[cq*16 + q*4 + j][r] = f2bf(v[j]);
    }
    __syncthreads();
    int c  = tid >> 2;
    int rq = tid & 3;
    short8 o0 = *reinterpret_cast<const short8*>(&T[c][rq*16]);
    short8 o1 = *reinterpret_cast<const short8*>(&T[c][rq*16 + 8]);
    unsigned short* dst = WT + (size_t)(n0 + c) * K + k0 + rq*16;
    *reinterpret_cast<short8*>(dst)     = o0;
    *reinterpret_cast<short8*>(dst + 8) = o1;
}

// ---------------------------------------------------------------------------
// Y = A[M,K](bf16) @ BT[N,K]^T(bf16) + bias(f32).  128x128 tile, BK=64,
// 4 waves (2x2), double-buffered global_load_lds (1 barrier/K-tile),
// pre-swizzled source + swizzled ds_read. XCD-aware block swizzle.
// FUSE: also write vtg[b][h][d][s] (bf16 V^T) and f32 present k/v slices.
// ---------------------------------------------------------------------------
template<int Y_F32, int FUSE>
__global__ __launch_bounds__(256) void gemm_bt_kernel(
    const unsigned short* __restrict__ A, const unsigned short* __restrict__ BT,
    const float* __restrict__ bias, void* __restrict__ Yv,
    unsigned short* __restrict__ vtg, float* __restrict__ pres,
    int M, int N, int K)
{
    __shared__ unsigned short sA[2][128*64];
    __shared__ unsigned short sB[2][128*64];

    const int tid = threadIdx.x, lane = tid & 63, w = tid >> 6;
    const int l15 = lane & 15, lg = lane >> 4;

    // XCD-aware swizzle: bid -> (bid%8)*(nwg/8) + bid/8
    const int nwg = gridDim.x * gridDim.y;
    const int bid = blockIdx.y * gridDim.x + blockIdx.x;
    const int swz = (bid & 7) * (nwg >> 3) + (bid >> 3);
    const int n0 = (swz % gridDim.x) * 128;
    const int m0 = (swz / gridDim.x) * 128;

    const int wr = w >> 1, wc = w & 1;

    f32x4 acc[4][4];
    #pragma unroll
    for (int m = 0; m < 4; ++m)
        #pragma unroll
        for (int n = 0; n < 4; ++n) acc[m][n] = f32x4{0,0,0,0};

    const int ldrow = (lane >> 3);
    const int slot  = lane & 7;
    const int nkt = K >> 6;

    // prologue: stage k-tile 0 into buf 0
    #pragma unroll
    for (int i = 0; i < 4; ++i) {
        int kb  = w*4 + i;
        int row = kb*8 + ldrow;
        int sc  = slot ^ (row & 7);
        gload_lds16(&A [(size_t)(m0 + row) * K + sc*8], &sA[0][kb*512]);
        gload_lds16(&BT[(size_t)(n0 + row) * K + sc*8], &sB[0][kb*512]);
    }
    __syncthreads();

    for (int kt = 0; kt < nkt; ++kt) {
        const int buf = kt & 1;

        if (kt + 1 < nkt) {   // prefetch next k-tile (async over compute)
            const int k1 = (kt + 1) << 6;
            #pragma unroll
            for (int i = 0; i < 4; ++i) {
                int kb  = w*4 + i;
                int row = kb*8 + ldrow;
                int sc  = slot ^ (row & 7);
                gload_lds16(&A [(size_t)(m0 + row) * K + k1 + sc*8], &sA[buf^1][kb*512]);
                gload_lds16(&BT[(size_t)(n0 + row) * K + k1 + sc*8], &sB[buf^1][kb*512]);
            }
        }

        #pragma unroll
        for (int kk = 0; kk < 2; ++kk) {
            short8 af[4], bfr[4];
            #pragma unroll
            for (int m = 0; m < 4; ++m) {
                int row = wr*64 + m*16 + l15;
                int ch  = (4*kk + lg) ^ (row & 7);
                af[m] = *reinterpret_cast<const short8*>(&sA[buf][row*64 + ch*8]);
            }
            #pragma unroll
            for (int n = 0; n < 4; ++n) {
                int row = wc*64 + n*16 + l15;
                int ch  = (4*kk + lg) ^ (row & 7);
                bfr[n] = *reinterpret_cast<const short8*>(&sB[buf][row*64 + ch*8]);
            }
            __builtin_amdgcn_s_setprio(1);
            #pragma unroll
            for (int m = 0; m < 4; ++m)
                #pragma unroll
                for (int n = 0; n < 4; ++n)
                    acc[m][n] = __builtin_amdgcn_mfma_f32_16x16x32_bf16(
                        af[m], bfr[n], acc[m][n], 0, 0, 0);
            __builtin_amdgcn_s_setprio(0);
        }
        __syncthreads();   // drains prefetch; protects buf for overwrite next iter
    }

    #pragma unroll
    for (int n = 0; n < 4; ++n) {
        int col = n0 + wc*64 + n*16 + l15;
        float bv = bias[col];
        #pragma unroll
        for (int m = 0; m < 4; ++m) {
            int row0 = m0 + wr*64 + m*16 + lg*4;
            float v0 = acc[m][n][0] + bv;
            float v1 = acc[m][n][1] + bv;
            float v2 = acc[m][n][2] + bv;
            float v3 = acc[m][n][3] + bv;
            if (Y_F32) {
                float* Y = (float*)Yv;
                Y[(size_t)(row0+0) * N + col] = v0;
                Y[(size_t)(row0+1) * N + col] = v1;
                Y[(size_t)(row0+2) * N + col] = v2;
                Y[(size_t)(row0+3) * N + col] = v3;
            } else {
                unsigned short* Y = (unsigned short*)Yv;
                Y[(size_t)(row0+0) * N + col] = f2bf(v0);
                Y[(size_t)(row0+1) * N + col] = f2bf(v1);
                Y[(size_t)(row0+2) * N + col] = f2bf(v2);
                Y[(size_t)(row0+3) * N + col] = f2bf(v3);
            }
            if (FUSE && n0 < D_MODEL) {   // V cols: vtg (bf16 V^T) + f32 present[1]
                int hh = col >> 6, dd = col & 63;
                int bb = row0 >> 11, ss = row0 & (SEQ - 1);
                short4v pk;
                pk[0] = (short)f2bf(v0); pk[1] = (short)f2bf(v1);
                pk[2] = (short)f2bf(v2); pk[3] = (short)f2bf(v3);
                *reinterpret_cast<short4v*>(
                    vtg + (((size_t)bb*HEADS + hh)*KD + dd)*SEQ + ss) = pk;
                float* pv = pres + (size_t)BATCH*HEADS*SEQ*KD
                          + (((size_t)bb*HEADS + hh)*SEQ + ss)*KD + dd;
                pv[0] = v0; pv[KD] = v1; pv[2*KD] = v2; pv[3*KD] = v3;
            }
            if (FUSE && n0 >= 2*D_MODEL) {  // K cols: f32 present[0]
                int rel = col - 2*D_MODEL;
                int hh = rel >> 6, dd = rel & 63;
                int bb = row0 >> 11, ss = row0 & (SEQ - 1);
                float* pk2 = pres + (((size_t)bb*HEADS + hh)*SEQ + ss)*KD + dd;
                pk2[0] = v0; pk2[KD] = v1; pk2[2*KD] = v2; pk2[3*KD] = v3;
            }
        }
    }
}

// ---------------------------------------------------------------------------
// Flash attention, swapped-operand 32x32 MFMA, merged 64-key stage.
// One 128-row q-tile per block -> 1024 blocks (4/CU resident); largest
// q-tiles dispatched first for load balance; XCD-grouped (bid&63 = (b,h)).
// ---------------------------------------------------------------------------
__global__ __launch_bounds__(256) void attn_kernel(
    const unsigned short* __restrict__ qkv,
    const unsigned short* __restrict__ vtg,
    unsigned short* __restrict__ aout)
{
    __shared__ unsigned short Kl[2][64*64];   // [key][d-chunk swz]
    __shared__ unsigned short Vl[2][64*64];   // [d][key-chunk swz]

    const int tid  = threadIdx.x;
    const int lane = tid & 63;
    const int w    = tid >> 6;
    const int l31  = lane & 31, hi = lane >> 5;

    const int bid = blockIdx.x;        // 0..1023
    const int hb  = bid & 63;          // (b,h): xcd = hb & 7, stable per (b,h)
    const int qb  = 15 - (bid >> 6);   // 15..0 : biggest tiles first
    const int h = hb & 15, b = hb >> 4;

    const unsigned short* base  = qkv + (size_t)b * SEQ * QKV_N;
    const unsigned short* vbase = vtg + ((size_t)b * HEADS + h) * KD * SEQ;
    const int qoff = D_MODEL + h*KD;
    const int koff = 2*D_MODEL + h*KD;

    const float SCALE2 = 0.125f * 1.44269504088896f;   // 0.18034
    const float THR_RAW = 44.36f;                      // 8 / SCALE2

    const int ldrow = lane >> 3;
    const int slot  = lane & 7;
    const int ksw   = l31 & 7;

    const int q0 = qb * 128;
    const int qrow  = q0 + w*32 + l31;
    const int qminw = q0 + w*32;

    short8 qf[4];
    #pragma unroll
    for (int ks = 0; ks < 4; ++ks)
        qf[ks] = *reinterpret_cast<const short8*>(
            base + (size_t)qrow * QKV_N + qoff + ks*16 + hi*8);

    f32x16 o0, o1;
    #pragma unroll
    for (int r = 0; r < 16; ++r) { o0[r] = 0.f; o1[r] = 0.f; }
    float m = -1e30f, msc = -1e30f * 0.180336887f, sr = 0.f;

    const int nt = 2*qb + 2;

    // prologue: stage tile 0
    #pragma unroll
    for (int i = 0; i < 2; ++i) {
        int kb = w*2 + i, row = kb*8 + ldrow, sc = slot ^ (row & 7);
        gload_lds16(&base[(size_t)row * QKV_N + koff + sc*8], &Kl[0][kb*512]);
        gload_lds16(&vbase[(size_t)row * SEQ + sc*8],         &Vl[0][kb*512]);
    }
    __syncthreads();

    for (int t = 0; t < nt; ++t) {
        const int buf = t & 1;

        if (t + 1 < nt) {   // prefetch next tile (async over compute)
            #pragma unroll
            for (int i = 0; i < 2; ++i) {
                int kb = w*2 + i, row = kb*8 + ldrow, sc = slot ^ (row & 7);
                gload_lds16(&base[(size_t)((t+1)*64 + row) * QKV_N + koff + sc*8],
                            &Kl[buf^1][kb*512]);
                gload_lds16(&vbase[(size_t)row * SEQ + (t+1)*64 + sc*8],
                            &Vl[buf^1][kb*512]);
            }
        }

        const int d0 = qminw - t*64;
        if (d0 > -32) {    // wave has work in this 64-key tile
            // ---- QK^T both 32-key halves ----
            f32x16 sa, sb;
            #pragma unroll
            for (int r = 0; r < 16; ++r) { sa[r] = 0.f; sb[r] = 0.f; }
            __builtin_amdgcn_s_setprio(1);
            #pragma unroll
            for (int ks = 0; ks < 4; ++ks) {
                short8 kf = *reinterpret_cast<const short8*>(
                    &Kl[buf][l31*64 + ((2*ks + hi) ^ ksw)*8]);
                sa = __builtin_amdgcn_mfma_f32_32x32x16_bf16(kf, qf[ks], sa, 0, 0, 0);
            }
            #pragma unroll
            for (int ks = 0; ks < 4; ++ks) {
                short8 kf = *reinterpret_cast<const short8*>(
                    &Kl[buf][(32 + l31)*64 + ((2*ks + hi) ^ ksw)*8]);
                sb = __builtin_amdgcn_mfma_f32_32x32x16_bf16(kf, qf[ks], sb, 0, 0, 0);
            }
            __builtin_amdgcn_s_setprio(0);

            // ---- causal mask (keys: A half = t*64+cr+4hi, B half = +32) ----
            if (d0 <= 32) {
                const int kqA = l31 + d0      - 4*hi;
                const int kqB = l31 + d0 - 32 - 4*hi;
                #pragma unroll
                for (int r = 0; r < 16; ++r) {
                    const int cr = (r & 3) + 8*(r >> 2);
                    if (d0 == 0) sa[r] = (cr <= kqA) ? sa[r] : -1e30f;
                    sb[r] = (cr <= kqB) ? sb[r] : -1e30f;
                }
            }

            // ---- max tree over 32 + cross-pair, defer-rescale ----
            float x[8];
            #pragma unroll
            for (int i = 0; i < 8; ++i)
                x[i] = fmaxf(fmaxf(sa[2*i], sa[2*i+1]), fmaxf(sb[2*i], sb[2*i+1]));
            float pm = fmaxf(fmaxf(fmaxf(x[0], x[1]), fmaxf(x[2], x[3])),
                             fmaxf(fmaxf(x[4], x[5]), fmaxf(x[6], x[7])));
            pm = pairmax(pm);
            if (!__all(pm <= m + THR_RAW)) {
                float mn  = fmaxf(m, pm);
                float fac = exp2f((m - mn) * SCALE2);
                sr *= fac;
                #pragma unroll
                for (int r = 0; r < 16; ++r) { o0[r] *= fac; o1[r] *= fac; }
                m = mn; msc = m * SCALE2;
            }

            // ---- exp + tree sum ----
            #pragma unroll
            for (int r = 0; r < 16; ++r) {
                sa[r] = exp2f(sa[r]*SCALE2 - msc);
                sb[r] = exp2f(sb[r]*SCALE2 - msc);
            }
            float u[8];
            #pragma unroll
            for (int i = 0; i < 8; ++i)
                u[i] = (sa[2*i] + sa[2*i+1]) + (sb[2*i] + sb[2*i+1]);
            float ts = ((u[0]+u[1]) + (u[2]+u[3])) + ((u[4]+u[5]) + (u[6]+u[7]));
            sr += pairsum(ts);

            // ---- pack P to bf16 ----
            u32 WA[8], WB[8];
            #pragma unroll
            for (int wi = 0; wi < 8; ++wi) {
                WA[wi] = cvtpk(sa[2*wi], sa[2*wi+1]);
                WB[wi] = cvtpk(sb[2*wi], sb[2*wi+1]);
            }

            // ---- PV: O^T += V^T @ P^T (proven shfl-based cross-half pack) ----
            #pragma unroll
            for (int h32 = 0; h32 < 2; ++h32) {
                #pragma unroll
                for (int ks = 0; ks < 2; ++ks) {
                    u32 W0 = h32 ? WB[4*ks+0] : WA[4*ks+0];
                    u32 W1 = h32 ? WB[4*ks+1] : WA[4*ks+1];
                    u32 W2 = h32 ? WB[4*ks+2] : WA[4*ks+2];
                    u32 W3 = h32 ? WB[4*ks+3] : WA[4*ks+3];
                    u32 s0 = hi ? W0 : W2;
                    u32 s1 = hi ? W1 : W3;
                    u32 r0 = (u32)__shfl_xor((int)s0, 32, 64);
                    u32 r1 = (u32)__shfl_xor((int)s1, 32, 64);
                    u32x4 wv;
                    wv[0] = hi ? r0 : W0;
                    wv[1] = hi ? r1 : W1;
                    wv[2] = hi ? W2 : r0;
                    wv[3] = hi ? W3 : r1;
                    short8 pfrag = __builtin_bit_cast(short8, wv);
                    __builtin_amdgcn_s_setprio(1);
                    #pragma unroll
                    for (int dt = 0; dt < 2; ++dt) {
                        short8 vf = *reinterpret_cast<const short8*>(
                            &Vl[buf][(dt*32 + l31)*64 + ((4*h32 + 2*ks + hi) ^ ksw)*8]);
                        if (dt == 0)
                            o0 = __builtin_amdgcn_mfma_f32_32x32x16_bf16(vf, pfrag, o0, 0, 0, 0);
                        else
                            o1 = __builtin_amdgcn_mfma_f32_32x32x16_bf16(vf, pfrag, o1, 0, 0, 0);
                    }
                    __builtin_amdgcn_s_setprio(0);
                }
            }
        }
        __syncthreads();
    }

    // ---- epilogue ----
    const float inv = 1.0f / sr;
    unsigned short* orow = aout + ((size_t)b * SEQ + qrow) * D_MODEL + h*KD;
    #pragma unroll
    for (int dt = 0; dt < 2; ++dt) {
        #pragma unroll
        for (int g = 0; g < 4; ++g) {
            short4v pk;
            #pragma unroll
            for (int j = 0; j < 4; ++j) {
                float v = (dt == 0 ? o0[4*g + j] : o1[4*g + j]) * inv;
                pk[j] = (short)f2bf(v);
            }
            *reinterpret_cast<short4v*>(orow + dt*32 + 8*g + 4*hi) = pk;
        }
    }
}

// ---------------------------------------------------------------------------
extern "C" void kernel_launch(void* const* d_in, const int* in_sizes, int n_in,
                              void* d_out, int out_size, void* d_ws, size_t ws_size,
                              hipStream_t stream)
{
    const float* x      = (const float*)d_in[0];
    const float* W_attn = (const float*)d_in[1];
    const float* b_attn = (const float*)d_in[2];
    const float* W_proj = (const float*)d_in[3];
    const float* b_proj = (const float*)d_in[4];
    float* out = (float*)d_out;

    unsigned short* qkv  = (unsigned short*)d_ws;                  // [8192][3072]
    unsigned short* xbf  = qkv + (size_t)NTOK * QKV_N;             // [8192][1024] (= aout later)
    unsigned short* aout = xbf;
    unsigned short* WT   = xbf + (size_t)NTOK * D_MODEL;           // [3072][1024]
    unsigned short* WpT  = WT + (size_t)QKV_N * D_MODEL;           // [1024][1024]
    unsigned short* vtg  = WpT + (size_t)D_MODEL * D_MODEL;        // [4][16][64][2048]
    float* pres = out + (size_t)NTOK * D_MODEL;                    // [2,4,16,2048,64] f32

    cvt_kernel<<<(NTOK * D_MODEL / 8) / 256, 256, 0, stream>>>(x, xbf);
    dim3 gt1(QKV_N / 64, D_MODEL / 64);
    transpose_kernel<<<gt1, 256, 0, stream>>>(W_attn, WT, D_MODEL, QKV_N);
    dim3 gt2(D_MODEL / 64, D_MODEL / 64);
    transpose_kernel<<<gt2, 256, 0, stream>>>(W_proj, WpT, D_MODEL, D_MODEL);

    // qkv = x @ W_attn + b_attn  (+ fused V^T copy and f32 present k/v)
    dim3 g1(QKV_N / 128, NTOK / 128);
    gemm_bt_kernel<0, 1><<<g1, 256, 0, stream>>>(xbf, WT, b_attn, qkv, vtg, pres,
                                                 NTOK, QKV_N, D_MODEL);

    // causal attention (1024 blocks, biggest-first, XCD-grouped)
    attn_kernel<<<1024, 256, 0, stream>>>(qkv, vtg, aout);

    // out = aout @ W_proj + b_proj
    dim3 g2(D_MODEL / 128, NTOK / 128);
    gemm_bt_kernel<1, 0><<<g2, 256, 0, stream>>>(aout, WpT, b_proj, out,
                                                 nullptr, nullptr,
                                                 NTOK, D_MODEL, D_MODEL);
}